// Round 2
// baseline (448.911 us; speedup 1.0000x reference)
//
#include <hip/hip_runtime.h>
#include <math.h>

// Problem constants
#define BB 4
#define TT 2048
#define CC 1024
#define HH 16
#define F3 3072          // 3*C
#define NTOK (BB*TT)     // 8192
#define KDIM 1024

typedef __attribute__((ext_vector_type(8))) short short8;            // 8 bf16
typedef __attribute__((ext_vector_type(8))) unsigned short ushort8;
typedef __attribute__((ext_vector_type(4))) unsigned short ushort4v;
typedef __attribute__((ext_vector_type(4))) float float4v;

static __device__ __forceinline__ unsigned short f2bf(float x) {
    union { float f; unsigned u; } v; v.f = x;
    unsigned r = v.u + 0x7fffu + ((v.u >> 16) & 1u);
    return (unsigned short)(r >> 16);
}
static __device__ __forceinline__ float bf2f(unsigned short h) {
    union { unsigned u; float f; } v; v.u = ((unsigned)h) << 16;
    return v.f;
}

// async 16B/lane global->LDS DMA; LDS dest = base + lane*16 (wave-uniform base)
static __device__ __forceinline__ void async16(const void* g, void* l) {
    __builtin_amdgcn_global_load_lds(
        (const __attribute__((address_space(1))) unsigned int*)g,
        (__attribute__((address_space(3))) unsigned int*)l, 16, 0, 0);
}

// DPP cross-lane (VALU pipe): ror8/ror4 + quad_perm xor2/xor1 = 16-lane butterfly
template <int C>
static __device__ __forceinline__ float dppf(float x) {
    return __int_as_float(
        __builtin_amdgcn_update_dpp(0, __float_as_int(x), C, 0xf, 0xf, true));
}
static __device__ __forceinline__ float red16_sum(float v) {
    v += dppf<0x128>(v);
    v += dppf<0x124>(v);
    v += dppf<0x4E>(v);
    v += dppf<0xB1>(v);
    return v;
}

#if __has_builtin(__builtin_amdgcn_exp2f)
#define EXP2(x) __builtin_amdgcn_exp2f(x)
#else
#define EXP2(x) __expf((x) * 0.6931471805599453f)
#endif

#define BAR()  asm volatile("s_barrier" ::: "memory")
#define VMW(n) asm volatile("s_waitcnt vmcnt(" #n ")" ::: "memory")

// ---------------------------------------------------------------------------
// prep_w: W[K,N] fp32 -> WtH/WtL [N][K] bf16 hi/lo (transpose + split).
// ---------------------------------------------------------------------------
__global__ __launch_bounds__(256) void prep_w(
    const float* __restrict__ W, unsigned short* __restrict__ WtH,
    unsigned short* __restrict__ WtL, int N)
{
    __shared__ float Ls[64][65];
    const int t = threadIdx.x;
    const int n0 = blockIdx.x * 64, k0 = blockIdx.y * 64;
    const int cc = t & 63, rr = t >> 6;
    #pragma unroll
    for (int i = 0; i < 16; ++i) {
        const int row = rr + 4 * i;
        Ls[row][cc] = W[(long)(k0 + row) * N + n0 + cc];
    }
    __syncthreads();
    const int n = t >> 2, seg = (t & 3) << 4;
    ushort8 h0, h1, l0, l1;
    #pragma unroll
    for (int j = 0; j < 8; ++j) {
        float x0 = Ls[seg + j][n];
        h0[j] = f2bf(x0); l0[j] = f2bf(x0 - bf2f(h0[j]));
        float x1 = Ls[seg + 8 + j][n];
        h1[j] = f2bf(x1); l1[j] = f2bf(x1 - bf2f(h1[j]));
    }
    const long o = (long)(n0 + n) * KDIM + k0 + seg;
    *(ushort8*)(WtH + o) = h0;     *(ushort8*)(WtH + o + 8) = h1;
    *(ushort8*)(WtL + o) = l0;     *(ushort8*)(WtL + o + 8) = l1;
}

// ---------------------------------------------------------------------------
// split_f32: X fp32 -> XH/XL bf16 hi/lo, elementwise.
// ---------------------------------------------------------------------------
__global__ __launch_bounds__(256) void split_f32(
    const float* __restrict__ X, unsigned short* __restrict__ XH,
    unsigned short* __restrict__ XL)
{
    const long i = (long)blockIdx.x * 256 + threadIdx.x;
    const float4 v = ((const float4*)X)[i];
    ushort4v h, lo;
    h[0] = f2bf(v.x); lo[0] = f2bf(v.x - bf2f(h[0]));
    h[1] = f2bf(v.y); lo[1] = f2bf(v.y - bf2f(h[1]));
    h[2] = f2bf(v.z); lo[2] = f2bf(v.z - bf2f(h[2]));
    h[3] = f2bf(v.w); lo[3] = f2bf(v.w - bf2f(h[3]));
    ((ushort4v*)XH)[i] = h;
    ((ushort4v*)XL)[i] = lo;
}

// ---------------------------------------------------------------------------
// gemm_split (reverted to R10): out[M,N] = (AH+AL)[M,K] @ (BH+BL)^T[N,K] +
// bias, 3-term split-bf16 MFMA. 128x128 tile, BK=32, 4 waves,
// global_load_lds staging with XOR-swizzled unpadded LDS.
// R11's 8-phase/counted-vmcnt restructure was NULL at this tile size
// (169 vs 163 us, MfmaUtil 41 vs 43, FETCH doubled at 1 block/CU) -> revert.
// ---------------------------------------------------------------------------
__global__ __launch_bounds__(256) void gemm_split(
    const unsigned short* __restrict__ AH, const unsigned short* __restrict__ AL,
    const unsigned short* __restrict__ BH, const unsigned short* __restrict__ BL,
    const float* __restrict__ bias, void* __restrict__ outp,
    unsigned short* __restrict__ VTp, int N, int mode)
{
    __shared__ __align__(16) unsigned short sAH[128 * 32];
    __shared__ __align__(16) unsigned short sAL[128 * 32];
    __shared__ __align__(16) unsigned short sBH[128 * 32];
    __shared__ __align__(16) unsigned short sBL[128 * 32];

    const int tid = threadIdx.x;
    const int n0 = blockIdx.x * 128, m0 = blockIdx.y * 128;
    const int lane = tid & 63, w = tid >> 6;
    const int wm = w >> 1, wn = w & 1;
    const int l = lane & 15, quad = lane >> 4;

    unsigned short* const sbuf = (w == 0) ? sAH : (w == 1) ? sAL
                               : (w == 2) ? sBH : sBL;
    const unsigned short* const gsrc =
        (w == 0) ? AH + (long)m0 * KDIM : (w == 1) ? AL + (long)m0 * KDIM
      : (w == 2) ? BH + (long)n0 * KDIM : BL + (long)n0 * KDIM;
    const int lrow = lane >> 2;
    const int lseg = ((lane & 3) - (lane >> 3)) & 3;
    const unsigned short* const gbase = gsrc + (long)lrow * KDIM + lseg * 8;
    unsigned short* const lbase = sbuf + lane * 8;

    const int swz = ((quad + (l >> 1)) & 3) * 8;

    float4v acc[4][4];
    #pragma unroll
    for (int mt = 0; mt < 4; ++mt)
        #pragma unroll
        for (int nt = 0; nt < 4; ++nt)
            acc[mt][nt] = (float4v){0.f, 0.f, 0.f, 0.f};

    for (int k0 = 0; k0 < KDIM; k0 += 32) {
        #pragma unroll
        for (int i = 0; i < 8; ++i)
            async16(gbase + (long)i * 16 * KDIM + k0, lbase + i * 512);
        __syncthreads();

        short8 fah[4], fal[4];
        #pragma unroll
        for (int mt = 0; mt < 4; ++mt) {
            const int off = (wm * 64 + mt * 16 + l) * 32 + swz;
            fah[mt] = *(const short8*)&sAH[off];
            fal[mt] = *(const short8*)&sAL[off];
        }
        #pragma unroll
        for (int nt = 0; nt < 4; ++nt) {
            const int off = (wn * 64 + nt * 16 + l) * 32 + swz;
            const short8 fbh = *(const short8*)&sBH[off];
            const short8 fbl = *(const short8*)&sBL[off];
            #pragma unroll
            for (int mt = 0; mt < 4; ++mt) {
                acc[mt][nt] = __builtin_amdgcn_mfma_f32_16x16x32_bf16(fah[mt], fbh, acc[mt][nt], 0, 0, 0);
                acc[mt][nt] = __builtin_amdgcn_mfma_f32_16x16x32_bf16(fah[mt], fbl, acc[mt][nt], 0, 0, 0);
                acc[mt][nt] = __builtin_amdgcn_mfma_f32_16x16x32_bf16(fal[mt], fbh, acc[mt][nt], 0, 0, 0);
            }
        }
        __syncthreads();
    }

    #pragma unroll
    for (int nt = 0; nt < 4; ++nt) {
        const int col = n0 + wn * 64 + nt * 16 + l;
        const float bv = bias[col];
        if (mode == 0) {
            #pragma unroll
            for (int mt = 0; mt < 4; ++mt)
                #pragma unroll
                for (int i = 0; i < 4; ++i) {
                    const long row = m0 + wm * 64 + mt * 16 + quad * 4 + i;
                    ((float*)outp)[row * N + col] = acc[mt][nt][i] + bv;
                }
        } else if (col < 2048) {
            const float sc = (col < 1024) ? 0.18033688011112042f : 1.0f;  // 0.125*log2(e)
            #pragma unroll
            for (int mt = 0; mt < 4; ++mt)
                #pragma unroll
                for (int i = 0; i < 4; ++i) {
                    const long row = m0 + wm * 64 + mt * 16 + quad * 4 + i;
                    ((unsigned short*)outp)[row * N + col] = f2bf((acc[mt][nt][i] + bv) * sc);
                }
        } else {
            const int d = col & 63;
            const int hh = (col >> 6) - 32;
            const int bb = m0 >> 11;
            const long vtoff = ((long)(bb * HH + hh) * 64 + d) * TT;
            #pragma unroll
            for (int mt = 0; mt < 4; ++mt) {
                const int t0 = (m0 & 2047) + wm * 64 + mt * 16 + quad * 4;
                ushort4v pk;
                #pragma unroll
                for (int i = 0; i < 4; ++i) pk[i] = f2bf(acc[mt][nt][i] + bv);
                *(ushort4v*)(VTp + vtoff + t0) = pk;
            }
        }
    }
}

// ---------------------------------------------------------------------------
// Flash attention, bf16 MFMA. R12: double-buffered K/V with counted vmcnt.
//  * R10's per-tile __syncthreads() drained vmcnt(0) -> full L2/HBM latency
//    exposed 32x per block. Now: stage tile t+1 into buf^1 BEFORE computing
//    tile t; wait with vmcnt(4) (only tile t's 4 loads, t+1's stay in
//    flight); raw s_barrier pairs (arrive / release). T14/T3-lite.
//  * s_setprio(1) around QK^T and PV MFMA clusters (T5, +4-7% attn m191).
//  * Math, LDS swizzle, fixed-max softmax, epilogue: bit-identical to R10.
//  * LDS 33 -> 49 KB (3 blocks/CU instead of 4); prefetch replaces the TLP.
//  * Safety: all ds_reads are consumed by MFMAs/VALU inside the phase
//    (compiler waits lgkmcnt before use), so lanes reach the release
//    barrier with no LDS reads in flight; Ps/Qs stripes are wave-private.
// ---------------------------------------------------------------------------
#define STAGEKV(k0, b) do { \
    async16(qkv + (base + (k0) + r0) * F3 + 1024 + hoff + s0 * 8, &Ks[b][u0 * 8]); \
    async16(qkv + (base + (k0) + r1) * F3 + 1024 + hoff + s1 * 8, &Ks[b][u1 * 8]); \
    async16(VT + vtbase + (long)r0 * TT + (k0) + s0 * 8, &Vs[b][u0 * 8]); \
    async16(VT + vtbase + (long)r1 * TT + (k0) + s1 * 8, &Vs[b][u1 * 8]); \
  } while (0)

#define ATTN_TILE(cur) do { \
    float4v sA[4]; \
    _Pragma("unroll") for (int nt = 0; nt < 4; ++nt) \
        sA[nt] = (float4v){0.f, 0.f, 0.f, 0.f}; \
    __builtin_amdgcn_s_setprio(1); \
    _Pragma("unroll") for (int kit = 0; kit < 2; ++kit) { \
        const int seg = ((kit * 4 + quad) ^ xs) * 8; \
        const short8 qa = *(const short8*)&Qs[(qbase + l) * 64 + seg]; \
        _Pragma("unroll") for (int nt = 0; nt < 4; ++nt) { \
            const short8 kb = *(const short8*)&Ks[cur][(16 * nt + l) * 64 + seg]; \
            sA[nt] = __builtin_amdgcn_mfma_f32_16x16x32_bf16(qa, kb, sA[nt], 0, 0, 0); \
        } \
    } \
    __builtin_amdgcn_s_setprio(0); \
    _Pragma("unroll") for (int nt = 0; nt < 4; ++nt) { \
        _Pragma("unroll") for (int i = 0; i < 4; ++i) { \
            const float p = EXP2(fminf(sA[nt][i], 80.f)); \
            const unsigned pu = __float_as_uint(p); \
            l_part[i] += __uint_as_float(pu & 0xFFFF0000u); \
            Ps[(qbase + quad * 4 + i) * 72 + 16 * nt + l] = \
                (unsigned short)(pu >> 16); \
        } \
    } \
    __builtin_amdgcn_s_setprio(1); \
    _Pragma("unroll") for (int kit = 0; kit < 2; ++kit) { \
        const short8 pa = *(const short8*)&Ps[(qbase + l) * 72 + kit * 32 + quad * 8]; \
        const int seg = ((kit * 4 + quad) ^ xs) * 8; \
        _Pragma("unroll") for (int dt = 0; dt < 4; ++dt) { \
            const short8 vb = *(const short8*)&Vs[cur][(16 * dt + l) * 64 + seg]; \
            acc[dt] = __builtin_amdgcn_mfma_f32_16x16x32_bf16(pa, vb, acc[dt], 0, 0, 0); \
        } \
    } \
    __builtin_amdgcn_s_setprio(0); \
  } while (0)

__global__ __attribute__((amdgpu_flat_work_group_size(256, 256),
                          amdgpu_waves_per_eu(4, 4)))
void attn_kernel(const unsigned short* __restrict__ qkv,
                 const unsigned short* __restrict__ VT,
                 unsigned short* __restrict__ yH,
                 unsigned short* __restrict__ yL)
{
    __shared__ __align__(16) unsigned short Qs[64 * 64];
    __shared__ __align__(16) unsigned short Ks[2][64 * 64];
    __shared__ __align__(16) unsigned short Vs[2][64 * 64];
    __shared__ __align__(16) unsigned short Ps[64 * 72];

    const int tid = threadIdx.x;
    const int q0 = blockIdx.x * 64;
    const int bh = blockIdx.y;
    const int b = bh >> 4;
    const int hoff = (bh & 15) * 64;
    const long base = (long)(b * TT);
    const long vtbase = (long)bh * 64 * TT;

    const int lane = tid & 63;
    const int wv = tid >> 6;
    const int l = lane & 15;
    const int quad = lane >> 4;
    const int qbase = wv * 16;
    const int xs = l & 7;

    const int u0 = (wv << 7) + lane, u1 = u0 + 64;
    const int r0 = u0 >> 3, s0 = (u0 & 7) ^ (r0 & 7);
    const int r1 = u1 >> 3, s1 = (u1 & 7) ^ (r1 & 7);

    // Q staging (wave-private stripe of Qs; covered by the first vmcnt wait)
    async16(qkv + (base + q0 + r0) * F3 + hoff + s0 * 8, &Qs[u0 * 8]);
    async16(qkv + (base + q0 + r1) * F3 + hoff + s1 * 8, &Qs[u1 * 8]);

    float4v acc[4];
    #pragma unroll
    for (int dt = 0; dt < 4; ++dt) acc[dt] = (float4v){0.f, 0.f, 0.f, 0.f};
    float l_part[4] = {0.f, 0.f, 0.f, 0.f};   // per-lane partial sum of masked p

    // prologue: tile 0 -> buf 0
    STAGEKV(0, 0);

    #pragma unroll 1
    for (int t = 0; t < TT / 64 - 1; ++t) {
        const int cur = t & 1;
        STAGEKV((t + 1) * 64, cur ^ 1);   // issue next tile (buf released at
                                          // the previous iteration's BAR)
        VMW(4);                           // tile t landed (self); t+1 in flight
        BAR();                            // all waves: tile t visible
        ATTN_TILE(cur);
        BAR();                            // release buf cur^1 for re-staging
    }
    // final tile (t = 31, cur = 1): drain, no staging
    VMW(0);
    BAR();
    ATTN_TILE(1);

    // ---- one deferred 16-lane reduction, normalize, write y hi/lo ----
    #pragma unroll
    for (int i = 0; i < 4; ++i) {
        const float inv_l = 1.f / red16_sum(l_part[i]);
        const long row = base + q0 + qbase + quad * 4 + i;
        #pragma unroll
        for (int dt = 0; dt < 4; ++dt) {
            const float o = acc[dt][i] * inv_l;
            const unsigned short hh = f2bf(o);
            yH[row * CC + hoff + 16 * dt + l] = hh;
            yL[row * CC + hoff + 16 * dt + l] = f2bf(o - bf2f(hh));
        }
    }
}

extern "C" void kernel_launch(void* const* d_in, const int* in_sizes, int n_in,
                              void* d_out, int out_size, void* d_ws, size_t ws_size,
                              hipStream_t stream) {
    const float* x      = (const float*)d_in[0];
    const float* w_attn = (const float*)d_in[1];
    const float* b_attn = (const float*)d_in[2];
    const float* w_proj = (const float*)d_in[3];
    const float* b_proj = (const float*)d_in[4];
    float* out = (float*)d_out;

    // ws layout (bytes):
    // qkv 50.3MB | VT 16.8 | xyH 16.8 | xyL 16.8 | WaH 6.3 | WaL 6.3 |
    // WpH 2.1 | WpL 2.1  => ~117.5 MB
    char* wsb = (char*)d_ws;
    unsigned short* qkv = (unsigned short*)(wsb);
    unsigned short* VT  = (unsigned short*)(wsb + 50331648);
    unsigned short* xyH = (unsigned short*)(wsb + 67108864);
    unsigned short* xyL = (unsigned short*)(wsb + 83886080);
    unsigned short* WaH = (unsigned short*)(wsb + 100663296);
    unsigned short* WaL = (unsigned short*)(wsb + 106954752);
    unsigned short* WpH = (unsigned short*)(wsb + 113246208);
    unsigned short* WpL = (unsigned short*)(wsb + 115343360);

    // 0) weight transpose+split, x split
    prep_w<<<dim3(F3 / 64, KDIM / 64), 256, 0, stream>>>(w_attn, WaH, WaL, F3);
    prep_w<<<dim3(CC / 64, KDIM / 64), 256, 0, stream>>>(w_proj, WpH, WpL, CC);
    split_f32<<<(NTOK * CC / 4) / 256, 256, 0, stream>>>(x, xyH, xyL);

    // 1) qkv = x @ w_attn + b_attn  (Q scaled by 0.125*log2e, V -> VT)
    gemm_split<<<dim3(F3 / 128, NTOK / 128), 256, 0, stream>>>(
        xyH, xyL, WaH, WaL, b_attn, qkv, VT, F3, 1);

    // 2) attention -> y (bf16 hi/lo; overwrites x-split which is dead)
    attn_kernel<<<dim3(TT / 64, BB * HH), 256, 0, stream>>>(qkv, VT, xyH, xyL);

    // 3) out (fp32) = y @ w_proj + b_proj
    gemm_split<<<dim3(CC / 128, NTOK / 128), 256, 0, stream>>>(
        xyH, xyL, WpH, WpL, b_proj, out, (unsigned short*)nullptr, CC, 0);
}

// Round 3
// 425.012 us; speedup vs baseline: 1.0562x; 1.0562x over previous
//
#include <hip/hip_runtime.h>
#include <math.h>

// Problem constants
#define BB 4
#define TT 2048
#define CC 1024
#define HH 16
#define F3 3072          // 3*C
#define NTOK (BB*TT)     // 8192
#define KDIM 1024

typedef __attribute__((ext_vector_type(8))) short short8;            // 8 bf16
typedef __attribute__((ext_vector_type(8))) unsigned short ushort8;
typedef __attribute__((ext_vector_type(4))) unsigned short ushort4v;
typedef __attribute__((ext_vector_type(4))) float float4v;

static __device__ __forceinline__ unsigned short f2bf(float x) {
    union { float f; unsigned u; } v; v.f = x;
    unsigned r = v.u + 0x7fffu + ((v.u >> 16) & 1u);
    return (unsigned short)(r >> 16);
}
static __device__ __forceinline__ float bf2f(unsigned short h) {
    union { unsigned u; float f; } v; v.u = ((unsigned)h) << 16;
    return v.f;
}

// async 16B/lane global->LDS DMA; LDS dest = base + lane*16 (wave-uniform base)
static __device__ __forceinline__ void async16(const void* g, void* l) {
    __builtin_amdgcn_global_load_lds(
        (const __attribute__((address_space(1))) unsigned int*)g,
        (__attribute__((address_space(3))) unsigned int*)l, 16, 0, 0);
}

// DPP cross-lane (VALU pipe): ror8/ror4 + quad_perm xor2/xor1 = 16-lane butterfly
template <int C>
static __device__ __forceinline__ float dppf(float x) {
    return __int_as_float(
        __builtin_amdgcn_update_dpp(0, __float_as_int(x), C, 0xf, 0xf, true));
}
static __device__ __forceinline__ float red16_sum(float v) {
    v += dppf<0x128>(v);
    v += dppf<0x124>(v);
    v += dppf<0x4E>(v);
    v += dppf<0xB1>(v);
    return v;
}

#if __has_builtin(__builtin_amdgcn_exp2f)
#define EXP2(x) __builtin_amdgcn_exp2f(x)
#else
#define EXP2(x) __expf((x) * 0.6931471805599453f)
#endif

#define BAR()  asm volatile("s_barrier" ::: "memory")
#define VMW(n) asm volatile("s_waitcnt vmcnt(" #n ")" ::: "memory")

// ---------------------------------------------------------------------------
// prep_w: W[K,N] fp32 -> WtH/WtL [N][K] bf16 hi/lo (transpose + split).
// ---------------------------------------------------------------------------
__global__ __launch_bounds__(256) void prep_w(
    const float* __restrict__ W, unsigned short* __restrict__ WtH,
    unsigned short* __restrict__ WtL, int N)
{
    __shared__ float Ls[64][65];
    const int t = threadIdx.x;
    const int n0 = blockIdx.x * 64, k0 = blockIdx.y * 64;
    const int cc = t & 63, rr = t >> 6;
    #pragma unroll
    for (int i = 0; i < 16; ++i) {
        const int row = rr + 4 * i;
        Ls[row][cc] = W[(long)(k0 + row) * N + n0 + cc];
    }
    __syncthreads();
    const int n = t >> 2, seg = (t & 3) << 4;
    ushort8 h0, h1, l0, l1;
    #pragma unroll
    for (int j = 0; j < 8; ++j) {
        float x0 = Ls[seg + j][n];
        h0[j] = f2bf(x0); l0[j] = f2bf(x0 - bf2f(h0[j]));
        float x1 = Ls[seg + 8 + j][n];
        h1[j] = f2bf(x1); l1[j] = f2bf(x1 - bf2f(h1[j]));
    }
    const long o = (long)(n0 + n) * KDIM + k0 + seg;
    *(ushort8*)(WtH + o) = h0;     *(ushort8*)(WtH + o + 8) = h1;
    *(ushort8*)(WtL + o) = l0;     *(ushort8*)(WtL + o + 8) = l1;
}

// ---------------------------------------------------------------------------
// split_f32: X fp32 -> XH/XL bf16 hi/lo, elementwise.
// ---------------------------------------------------------------------------
__global__ __launch_bounds__(256) void split_f32(
    const float* __restrict__ X, unsigned short* __restrict__ XH,
    unsigned short* __restrict__ XL)
{
    const long i = (long)blockIdx.x * 256 + threadIdx.x;
    const float4 v = ((const float4*)X)[i];
    ushort4v h, lo;
    h[0] = f2bf(v.x); lo[0] = f2bf(v.x - bf2f(h[0]));
    h[1] = f2bf(v.y); lo[1] = f2bf(v.y - bf2f(h[1]));
    h[2] = f2bf(v.z); lo[2] = f2bf(v.z - bf2f(h[2]));
    h[3] = f2bf(v.w); lo[3] = f2bf(v.w - bf2f(h[3]));
    ((ushort4v*)XH)[i] = h;
    ((ushort4v*)XL)[i] = lo;
}

// ---------------------------------------------------------------------------
// gemm_split (R10 structure, unchanged): out[M,N] = (AH+AL)[M,K] @
// (BH+BL)^T[N,K] + bias, 3-term split-bf16 MFMA. 128x128 tile, BK=32,
// 4 waves, global_load_lds staging with XOR-swizzled unpadded LDS.
// (R11's 8-phase restructure was NULL at this tile size -> keep R10.)
// ---------------------------------------------------------------------------
__global__ __launch_bounds__(256) void gemm_split(
    const unsigned short* __restrict__ AH, const unsigned short* __restrict__ AL,
    const unsigned short* __restrict__ BH, const unsigned short* __restrict__ BL,
    const float* __restrict__ bias, void* __restrict__ outp,
    unsigned short* __restrict__ VTp, int N, int mode)
{
    __shared__ __align__(16) unsigned short sAH[128 * 32];
    __shared__ __align__(16) unsigned short sAL[128 * 32];
    __shared__ __align__(16) unsigned short sBH[128 * 32];
    __shared__ __align__(16) unsigned short sBL[128 * 32];

    const int tid = threadIdx.x;
    const int n0 = blockIdx.x * 128, m0 = blockIdx.y * 128;
    const int lane = tid & 63, w = tid >> 6;
    const int wm = w >> 1, wn = w & 1;
    const int l = lane & 15, quad = lane >> 4;

    unsigned short* const sbuf = (w == 0) ? sAH : (w == 1) ? sAL
                               : (w == 2) ? sBH : sBL;
    const unsigned short* const gsrc =
        (w == 0) ? AH + (long)m0 * KDIM : (w == 1) ? AL + (long)m0 * KDIM
      : (w == 2) ? BH + (long)n0 * KDIM : BL + (long)n0 * KDIM;
    const int lrow = lane >> 2;
    const int lseg = ((lane & 3) - (lane >> 3)) & 3;
    const unsigned short* const gbase = gsrc + (long)lrow * KDIM + lseg * 8;
    unsigned short* const lbase = sbuf + lane * 8;

    const int swz = ((quad + (l >> 1)) & 3) * 8;

    float4v acc[4][4];
    #pragma unroll
    for (int mt = 0; mt < 4; ++mt)
        #pragma unroll
        for (int nt = 0; nt < 4; ++nt)
            acc[mt][nt] = (float4v){0.f, 0.f, 0.f, 0.f};

    for (int k0 = 0; k0 < KDIM; k0 += 32) {
        #pragma unroll
        for (int i = 0; i < 8; ++i)
            async16(gbase + (long)i * 16 * KDIM + k0, lbase + i * 512);
        __syncthreads();

        short8 fah[4], fal[4];
        #pragma unroll
        for (int mt = 0; mt < 4; ++mt) {
            const int off = (wm * 64 + mt * 16 + l) * 32 + swz;
            fah[mt] = *(const short8*)&sAH[off];
            fal[mt] = *(const short8*)&sAL[off];
        }
        #pragma unroll
        for (int nt = 0; nt < 4; ++nt) {
            const int off = (wn * 64 + nt * 16 + l) * 32 + swz;
            const short8 fbh = *(const short8*)&sBH[off];
            const short8 fbl = *(const short8*)&sBL[off];
            #pragma unroll
            for (int mt = 0; mt < 4; ++mt) {
                acc[mt][nt] = __builtin_amdgcn_mfma_f32_16x16x32_bf16(fah[mt], fbh, acc[mt][nt], 0, 0, 0);
                acc[mt][nt] = __builtin_amdgcn_mfma_f32_16x16x32_bf16(fah[mt], fbl, acc[mt][nt], 0, 0, 0);
                acc[mt][nt] = __builtin_amdgcn_mfma_f32_16x16x32_bf16(fal[mt], fbh, acc[mt][nt], 0, 0, 0);
            }
        }
        __syncthreads();
    }

    #pragma unroll
    for (int nt = 0; nt < 4; ++nt) {
        const int col = n0 + wn * 64 + nt * 16 + l;
        const float bv = bias[col];
        if (mode == 0) {
            #pragma unroll
            for (int mt = 0; mt < 4; ++mt)
                #pragma unroll
                for (int i = 0; i < 4; ++i) {
                    const long row = m0 + wm * 64 + mt * 16 + quad * 4 + i;
                    ((float*)outp)[row * N + col] = acc[mt][nt][i] + bv;
                }
        } else if (col < 2048) {
            const float sc = (col < 1024) ? 0.18033688011112042f : 1.0f;  // 0.125*log2(e)
            #pragma unroll
            for (int mt = 0; mt < 4; ++mt)
                #pragma unroll
                for (int i = 0; i < 4; ++i) {
                    const long row = m0 + wm * 64 + mt * 16 + quad * 4 + i;
                    ((unsigned short*)outp)[row * N + col] = f2bf((acc[mt][nt][i] + bv) * sc);
                }
        } else {
            const int d = col & 63;
            const int hh = (col >> 6) - 32;
            const int bb = m0 >> 11;
            const long vtoff = ((long)(bb * HH + hh) * 64 + d) * TT;
            #pragma unroll
            for (int mt = 0; mt < 4; ++mt) {
                const int t0 = (m0 & 2047) + wm * 64 + mt * 16 + quad * 4;
                ushort4v pk;
                #pragma unroll
                for (int i = 0; i < 4; ++i) pk[i] = f2bf(acc[mt][nt][i] + bv);
                *(ushort4v*)(VTp + vtoff + t0) = pk;
            }
        }
    }
}

// ---------------------------------------------------------------------------
// Flash attention, bf16 MFMA. R13: attn was HBM-BOUND, not latency-bound
// (R11/R12 post-mortems): QBLK=64 -> 2048 blocks x 512KB K/V re-read =
// 1.07 GB = 170 us @ 6.3 TB/s == measured. Fix the traffic:
//  * QBLK 64 -> 256 (4 waves, 64 q-rows/wave as 4x 16-row sub-tiles; Q held
//    in registers as MFMA fragments): K/V traffic /4 -> 268 MB.
//  * T1 XCD swizzle: XCD k <- bh in [8k,8k+8) x 8 q-tiles; all 512 blocks
//    resident (2/CU); 8 same-bh blocks co-resident per XCD -> K/V tile hits
//    L2 7/8 of the time -> HBM ~50MB ideal.
//  * K/V double-buffer + vmcnt(4) kept: at 73KB LDS it costs no occupancy
//    (2 blocks/CU either way) and 8 waves/CU benefits from the prefetch.
//  * Math identities unchanged from R10: XOR-swizzled staging, exp2-domain
//    fixed-max softmax, truncation-consistent masked-l, deferred DPP
//    reduction. Ps stripe (16 rows/wave) reused across the 4 qt sub-tiles
//    (same-wave DS ops are program-ordered; R10 relied on the same).
// ---------------------------------------------------------------------------
#define STAGEKV(k0, bf) do { \
    async16(qkv + (base + (k0) + r0) * F3 + 1024 + hoff + s0 * 8, &Ks[bf][u0 * 8]); \
    async16(qkv + (base + (k0) + r1) * F3 + 1024 + hoff + s1 * 8, &Ks[bf][u1 * 8]); \
    async16(VT + vtbase + (long)r0 * TT + (k0) + s0 * 8, &Vs[bf][u0 * 8]); \
    async16(VT + vtbase + (long)r1 * TT + (k0) + s1 * 8, &Vs[bf][u1 * 8]); \
  } while (0)

#define ATTN_TILE(cur) do { \
    _Pragma("unroll") for (int qt = 0; qt < 4; ++qt) { \
        float4v sA[4]; \
        _Pragma("unroll") for (int nt = 0; nt < 4; ++nt) \
            sA[nt] = (float4v){0.f, 0.f, 0.f, 0.f}; \
        __builtin_amdgcn_s_setprio(1); \
        _Pragma("unroll") for (int kit = 0; kit < 2; ++kit) { \
            const int seg = ((kit * 4 + quad) ^ xs) * 8; \
            _Pragma("unroll") for (int nt = 0; nt < 4; ++nt) { \
                const short8 kb = *(const short8*)&Ks[cur][(16 * nt + l) * 64 + seg]; \
                sA[nt] = __builtin_amdgcn_mfma_f32_16x16x32_bf16(qa[qt][kit], kb, sA[nt], 0, 0, 0); \
            } \
        } \
        __builtin_amdgcn_s_setprio(0); \
        _Pragma("unroll") for (int nt = 0; nt < 4; ++nt) { \
            _Pragma("unroll") for (int i = 0; i < 4; ++i) { \
                const float p = EXP2(fminf(sA[nt][i], 80.f)); \
                const unsigned pu = __float_as_uint(p); \
                l_part[qt][i] += __uint_as_float(pu & 0xFFFF0000u); \
                Ps[(wv * 16 + quad * 4 + i) * 72 + 16 * nt + l] = \
                    (unsigned short)(pu >> 16); \
            } \
        } \
        __builtin_amdgcn_s_setprio(1); \
        _Pragma("unroll") for (int kit = 0; kit < 2; ++kit) { \
            const short8 pa = *(const short8*)&Ps[(wv * 16 + l) * 72 + kit * 32 + quad * 8]; \
            const int seg = ((kit * 4 + quad) ^ xs) * 8; \
            _Pragma("unroll") for (int dt = 0; dt < 4; ++dt) { \
                const short8 vb = *(const short8*)&Vs[cur][(16 * dt + l) * 64 + seg]; \
                acc[qt][dt] = __builtin_amdgcn_mfma_f32_16x16x32_bf16(pa, vb, acc[qt][dt], 0, 0, 0); \
            } \
        } \
        __builtin_amdgcn_s_setprio(0); \
    } \
  } while (0)

__global__ __attribute__((amdgpu_flat_work_group_size(256, 256),
                          amdgpu_waves_per_eu(2)))
void attn_kernel(const unsigned short* __restrict__ qkv,
                 const unsigned short* __restrict__ VT,
                 unsigned short* __restrict__ yH,
                 unsigned short* __restrict__ yL)
{
    __shared__ __align__(16) unsigned short Qs[256 * 64];       // 32 KB
    __shared__ __align__(16) unsigned short Ks[2][64 * 64];     // 16 KB
    __shared__ __align__(16) unsigned short Vs[2][64 * 64];     // 16 KB
    __shared__ __align__(16) unsigned short Ps[64 * 72];        //  9 KB

    const int tid = threadIdx.x;
    // T1 XCD swizzle (512 blocks, all resident at 2/CU): XCD k handles
    // bh in [8k, 8k+8), each with all 8 q-tiles -> per-XCD K/V working set
    // 4MB = L2; 8 same-bh blocks co-resident -> temporal L2 reuse.
    const int lid = blockIdx.x;
    const int work = (lid & 7) * 64 + (lid >> 3);
    const int q0 = (work & 7) * 256;
    const int bh = work >> 3;
    const int b = bh >> 4;
    const int hoff = (bh & 15) * 64;
    const long base = (long)(b * TT);
    const long vtbase = (long)bh * 64 * TT;

    const int lane = tid & 63;
    const int wv = tid >> 6;
    const int l = lane & 15;
    const int quad = lane >> 4;
    const int xs = l & 7;

    const int u0 = (wv << 7) + lane, u1 = u0 + 64;
    const int r0 = u0 >> 3, s0 = (u0 & 7) ^ (r0 & 7);
    const int r1 = u1 >> 3, s1 = (u1 & 7) ^ (r1 & 7);

    // ---- Q staging: 256 rows x 64, 8 slots/thread, same XOR layout ----
    #pragma unroll
    for (int i = 0; i < 8; ++i) {
        const int u = (wv << 9) + (i << 6) + lane;
        const int r = u >> 3, s = (u & 7) ^ (r & 7);
        async16(qkv + (base + q0 + r) * F3 + hoff + s * 8, &Qs[u * 8]);
    }
    STAGEKV(0, 0);
    VMW(0); BAR();

    // ---- Q fragments -> registers (Qs dead afterwards) ----
    short8 qa[4][2];
    #pragma unroll
    for (int qt = 0; qt < 4; ++qt)
        #pragma unroll
        for (int kit = 0; kit < 2; ++kit) {
            const int seg = ((kit * 4 + quad) ^ xs) * 8;
            qa[qt][kit] = *(const short8*)&Qs[(wv * 64 + qt * 16 + l) * 64 + seg];
        }

    float4v acc[4][4];
    float l_part[4][4];
    #pragma unroll
    for (int qt = 0; qt < 4; ++qt)
        #pragma unroll
        for (int dt = 0; dt < 4; ++dt) {
            acc[qt][dt] = (float4v){0.f, 0.f, 0.f, 0.f};
            l_part[qt][dt] = 0.f;
        }

    #pragma unroll 1
    for (int t = 0; t < TT / 64 - 1; ++t) {
        const int cur = t & 1;
        STAGEKV((t + 1) * 64, cur ^ 1);   // buf cur^1 released at prev BAR
        VMW(4);                           // tile t landed; t+1 in flight
        BAR();
        ATTN_TILE(cur);
        BAR();
    }
    VMW(0);
    BAR();
    ATTN_TILE(1);

    // ---- deferred 16-lane reductions, normalize, write y hi/lo ----
    #pragma unroll
    for (int qt = 0; qt < 4; ++qt)
        #pragma unroll
        for (int i = 0; i < 4; ++i) {
            const float inv_l = 1.f / red16_sum(l_part[qt][i]);
            const long row = base + q0 + wv * 64 + qt * 16 + quad * 4 + i;
            #pragma unroll
            for (int dt = 0; dt < 4; ++dt) {
                const float o = acc[qt][dt][i] * inv_l;
                const unsigned short hh = f2bf(o);
                yH[row * CC + hoff + 16 * dt + l] = hh;
                yL[row * CC + hoff + 16 * dt + l] = f2bf(o - bf2f(hh));
            }
        }
}

extern "C" void kernel_launch(void* const* d_in, const int* in_sizes, int n_in,
                              void* d_out, int out_size, void* d_ws, size_t ws_size,
                              hipStream_t stream) {
    const float* x      = (const float*)d_in[0];
    const float* w_attn = (const float*)d_in[1];
    const float* b_attn = (const float*)d_in[2];
    const float* w_proj = (const float*)d_in[3];
    const float* b_proj = (const float*)d_in[4];
    float* out = (float*)d_out;

    // ws layout (bytes):
    // qkv 50.3MB | VT 16.8 | xyH 16.8 | xyL 16.8 | WaH 6.3 | WaL 6.3 |
    // WpH 2.1 | WpL 2.1  => ~117.5 MB
    char* wsb = (char*)d_ws;
    unsigned short* qkv = (unsigned short*)(wsb);
    unsigned short* VT  = (unsigned short*)(wsb + 50331648);
    unsigned short* xyH = (unsigned short*)(wsb + 67108864);
    unsigned short* xyL = (unsigned short*)(wsb + 83886080);
    unsigned short* WaH = (unsigned short*)(wsb + 100663296);
    unsigned short* WaL = (unsigned short*)(wsb + 106954752);
    unsigned short* WpH = (unsigned short*)(wsb + 113246208);
    unsigned short* WpL = (unsigned short*)(wsb + 115343360);

    // 0) weight transpose+split, x split
    prep_w<<<dim3(F3 / 64, KDIM / 64), 256, 0, stream>>>(w_attn, WaH, WaL, F3);
    prep_w<<<dim3(CC / 64, KDIM / 64), 256, 0, stream>>>(w_proj, WpH, WpL, CC);
    split_f32<<<(NTOK * CC / 4) / 256, 256, 0, stream>>>(x, xyH, xyL);

    // 1) qkv = x @ w_attn + b_attn  (Q scaled by 0.125*log2e, V -> VT)
    gemm_split<<<dim3(F3 / 128, NTOK / 128), 256, 0, stream>>>(
        xyH, xyL, WaH, WaL, b_attn, qkv, VT, F3, 1);

    // 2) attention -> y (bf16 hi/lo; overwrites x-split which is dead)
    attn_kernel<<<dim3((TT / 256) * BB * HH), 256, 0, stream>>>(qkv, VT, xyH, xyL);

    // 3) out (fp32) = y @ w_proj + b_proj
    gemm_split<<<dim3(CC / 128, NTOK / 128), 256, 0, stream>>>(
        xyH, xyL, WpH, WpL, b_proj, out, (unsigned short*)nullptr, CC, 0);
}

// Round 4
// 409.943 us; speedup vs baseline: 1.0951x; 1.0368x over previous
//
#include <hip/hip_runtime.h>
#include <math.h>

// Problem constants
#define BB 4
#define TT 2048
#define CC 1024
#define HH 16
#define F3 3072          // 3*C
#define NTOK (BB*TT)     // 8192
#define KDIM 1024

typedef __attribute__((ext_vector_type(8))) short short8;            // 8 bf16
typedef __attribute__((ext_vector_type(8))) unsigned short ushort8;
typedef __attribute__((ext_vector_type(4))) unsigned short ushort4v;
typedef __attribute__((ext_vector_type(4))) float float4v;

static __device__ __forceinline__ unsigned short f2bf(float x) {
    union { float f; unsigned u; } v; v.f = x;
    unsigned r = v.u + 0x7fffu + ((v.u >> 16) & 1u);
    return (unsigned short)(r >> 16);
}
static __device__ __forceinline__ float bf2f(unsigned short h) {
    union { unsigned u; float f; } v; v.u = ((unsigned)h) << 16;
    return v.f;
}

// async 16B/lane global->LDS DMA; LDS dest = base + lane*16 (wave-uniform base)
static __device__ __forceinline__ void async16(const void* g, void* l) {
    __builtin_amdgcn_global_load_lds(
        (const __attribute__((address_space(1))) unsigned int*)g,
        (__attribute__((address_space(3))) unsigned int*)l, 16, 0, 0);
}

// DPP cross-lane (VALU pipe): ror8/ror4 + quad_perm xor2/xor1 = 16-lane butterfly
template <int C>
static __device__ __forceinline__ float dppf(float x) {
    return __int_as_float(
        __builtin_amdgcn_update_dpp(0, __float_as_int(x), C, 0xf, 0xf, true));
}
static __device__ __forceinline__ float red16_sum(float v) {
    v += dppf<0x128>(v);
    v += dppf<0x124>(v);
    v += dppf<0x4E>(v);
    v += dppf<0xB1>(v);
    return v;
}

#if __has_builtin(__builtin_amdgcn_exp2f)
#define EXP2(x) __builtin_amdgcn_exp2f(x)
#else
#define EXP2(x) __expf((x) * 0.6931471805599453f)
#endif

#define BAR()  asm volatile("s_barrier" ::: "memory")
#define VMW(n) asm volatile("s_waitcnt vmcnt(" #n ")" ::: "memory")

// ---------------------------------------------------------------------------
// prep_w: W[K,N] fp32 -> WtH/WtL [N][K] bf16 hi/lo (transpose + split).
// ---------------------------------------------------------------------------
__global__ __launch_bounds__(256) void prep_w(
    const float* __restrict__ W, unsigned short* __restrict__ WtH,
    unsigned short* __restrict__ WtL, int N)
{
    __shared__ float Ls[64][65];
    const int t = threadIdx.x;
    const int n0 = blockIdx.x * 64, k0 = blockIdx.y * 64;
    const int cc = t & 63, rr = t >> 6;
    #pragma unroll
    for (int i = 0; i < 16; ++i) {
        const int row = rr + 4 * i;
        Ls[row][cc] = W[(long)(k0 + row) * N + n0 + cc];
    }
    __syncthreads();
    const int n = t >> 2, seg = (t & 3) << 4;
    ushort8 h0, h1, l0, l1;
    #pragma unroll
    for (int j = 0; j < 8; ++j) {
        float x0 = Ls[seg + j][n];
        h0[j] = f2bf(x0); l0[j] = f2bf(x0 - bf2f(h0[j]));
        float x1 = Ls[seg + 8 + j][n];
        h1[j] = f2bf(x1); l1[j] = f2bf(x1 - bf2f(h1[j]));
    }
    const long o = (long)(n0 + n) * KDIM + k0 + seg;
    *(ushort8*)(WtH + o) = h0;     *(ushort8*)(WtH + o + 8) = h1;
    *(ushort8*)(WtL + o) = l0;     *(ushort8*)(WtL + o + 8) = l1;
}

// ---------------------------------------------------------------------------
// split_f32: X fp32 -> XH/XL bf16 hi/lo, elementwise.
// ---------------------------------------------------------------------------
__global__ __launch_bounds__(256) void split_f32(
    const float* __restrict__ X, unsigned short* __restrict__ XH,
    unsigned short* __restrict__ XL)
{
    const long i = (long)blockIdx.x * 256 + threadIdx.x;
    const float4 v = ((const float4*)X)[i];
    ushort4v h, lo;
    h[0] = f2bf(v.x); lo[0] = f2bf(v.x - bf2f(h[0]));
    h[1] = f2bf(v.y); lo[1] = f2bf(v.y - bf2f(h[1]));
    h[2] = f2bf(v.z); lo[2] = f2bf(v.z - bf2f(h[2]));
    h[3] = f2bf(v.w); lo[3] = f2bf(v.w - bf2f(h[3]));
    ((ushort4v*)XH)[i] = h;
    ((ushort4v*)XL)[i] = lo;
}

// ---------------------------------------------------------------------------
// gemm_split (R10 structure, unchanged): out[M,N] = (AH+AL)[M,K] @
// (BH+BL)^T[N,K] + bias, 3-term split-bf16 MFMA. 128x128 tile, BK=32,
// 4 waves, global_load_lds staging with XOR-swizzled unpadded LDS.
// ---------------------------------------------------------------------------
__global__ __launch_bounds__(256) void gemm_split(
    const unsigned short* __restrict__ AH, const unsigned short* __restrict__ AL,
    const unsigned short* __restrict__ BH, const unsigned short* __restrict__ BL,
    const float* __restrict__ bias, void* __restrict__ outp,
    unsigned short* __restrict__ VTp, int N, int mode)
{
    __shared__ __align__(16) unsigned short sAH[128 * 32];
    __shared__ __align__(16) unsigned short sAL[128 * 32];
    __shared__ __align__(16) unsigned short sBH[128 * 32];
    __shared__ __align__(16) unsigned short sBL[128 * 32];

    const int tid = threadIdx.x;
    const int n0 = blockIdx.x * 128, m0 = blockIdx.y * 128;
    const int lane = tid & 63, w = tid >> 6;
    const int wm = w >> 1, wn = w & 1;
    const int l = lane & 15, quad = lane >> 4;

    unsigned short* const sbuf = (w == 0) ? sAH : (w == 1) ? sAL
                               : (w == 2) ? sBH : sBL;
    const unsigned short* const gsrc =
        (w == 0) ? AH + (long)m0 * KDIM : (w == 1) ? AL + (long)m0 * KDIM
      : (w == 2) ? BH + (long)n0 * KDIM : BL + (long)n0 * KDIM;
    const int lrow = lane >> 2;
    const int lseg = ((lane & 3) - (lane >> 3)) & 3;
    const unsigned short* const gbase = gsrc + (long)lrow * KDIM + lseg * 8;
    unsigned short* const lbase = sbuf + lane * 8;

    const int swz = ((quad + (l >> 1)) & 3) * 8;

    float4v acc[4][4];
    #pragma unroll
    for (int mt = 0; mt < 4; ++mt)
        #pragma unroll
        for (int nt = 0; nt < 4; ++nt)
            acc[mt][nt] = (float4v){0.f, 0.f, 0.f, 0.f};

    for (int k0 = 0; k0 < KDIM; k0 += 32) {
        #pragma unroll
        for (int i = 0; i < 8; ++i)
            async16(gbase + (long)i * 16 * KDIM + k0, lbase + i * 512);
        __syncthreads();

        short8 fah[4], fal[4];
        #pragma unroll
        for (int mt = 0; mt < 4; ++mt) {
            const int off = (wm * 64 + mt * 16 + l) * 32 + swz;
            fah[mt] = *(const short8*)&sAH[off];
            fal[mt] = *(const short8*)&sAL[off];
        }
        #pragma unroll
        for (int nt = 0; nt < 4; ++nt) {
            const int off = (wn * 64 + nt * 16 + l) * 32 + swz;
            const short8 fbh = *(const short8*)&sBH[off];
            const short8 fbl = *(const short8*)&sBL[off];
            #pragma unroll
            for (int mt = 0; mt < 4; ++mt) {
                acc[mt][nt] = __builtin_amdgcn_mfma_f32_16x16x32_bf16(fah[mt], fbh, acc[mt][nt], 0, 0, 0);
                acc[mt][nt] = __builtin_amdgcn_mfma_f32_16x16x32_bf16(fah[mt], fbl, acc[mt][nt], 0, 0, 0);
                acc[mt][nt] = __builtin_amdgcn_mfma_f32_16x16x32_bf16(fal[mt], fbh, acc[mt][nt], 0, 0, 0);
            }
        }
        __syncthreads();
    }

    #pragma unroll
    for (int nt = 0; nt < 4; ++nt) {
        const int col = n0 + wn * 64 + nt * 16 + l;
        const float bv = bias[col];
        if (mode == 0) {
            #pragma unroll
            for (int mt = 0; mt < 4; ++mt)
                #pragma unroll
                for (int i = 0; i < 4; ++i) {
                    const long row = m0 + wm * 64 + mt * 16 + quad * 4 + i;
                    ((float*)outp)[row * N + col] = acc[mt][nt][i] + bv;
                }
        } else if (col < 2048) {
            const float sc = (col < 1024) ? 0.18033688011112042f : 1.0f;  // 0.125*log2(e)
            #pragma unroll
            for (int mt = 0; mt < 4; ++mt)
                #pragma unroll
                for (int i = 0; i < 4; ++i) {
                    const long row = m0 + wm * 64 + mt * 16 + quad * 4 + i;
                    ((unsigned short*)outp)[row * N + col] = f2bf((acc[mt][nt][i] + bv) * sc);
                }
        } else {
            const int d = col & 63;
            const int hh = (col >> 6) - 32;
            const int bb = m0 >> 11;
            const long vtoff = ((long)(bb * HH + hh) * 64 + d) * TT;
            #pragma unroll
            for (int mt = 0; mt < 4; ++mt) {
                const int t0 = (m0 & 2047) + wm * 64 + mt * 16 + quad * 4;
                ushort4v pk;
                #pragma unroll
                for (int i = 0; i < 4; ++i) pk[i] = f2bf(acc[mt][nt][i] + bv);
                *(ushort4v*)(VTp + vtoff + t0) = pk;
            }
        }
    }
}

// ---------------------------------------------------------------------------
// Flash attention, bf16 MFMA. R14: LDS-read traffic was the exposed
// bottleneck after R13 cut HBM (R13 post-mortem: 72 ds_read_b128 per
// wave-tile = 4.8 GB LDS reads ~ 90 us of LDS pipe). Fix: hoist the
// qt-invariant K/V fragments into registers:
//  * QK^T kit-outer: kb[4] read once per kit (8 reads/tile), all 4 qt
//    MFMA against it; sA[4][4] accumulates across both kits.
//  * vb[2][4] read once per tile (8 reads), held across the qt loop.
//  * per-qt: softmax -> Ps stripe write -> pa reads (8/tile) -> PV MFMA.
//  LDS reads/wave-tile: 72 -> 24. Everything else identical to R13:
//  QBLK=256, XCD swizzle, K/V double-buffer + vmcnt(4), fixed-max exp2
//  softmax with truncation-consistent masked-l, deferred DPP reduction.
// ---------------------------------------------------------------------------
#define STAGEKV(k0, bf) do { \
    async16(qkv + (base + (k0) + r0) * F3 + 1024 + hoff + s0 * 8, &Ks[bf][u0 * 8]); \
    async16(qkv + (base + (k0) + r1) * F3 + 1024 + hoff + s1 * 8, &Ks[bf][u1 * 8]); \
    async16(VT + vtbase + (long)r0 * TT + (k0) + s0 * 8, &Vs[bf][u0 * 8]); \
    async16(VT + vtbase + (long)r1 * TT + (k0) + s1 * 8, &Vs[bf][u1 * 8]); \
  } while (0)

#define ATTN_TILE(cur) do { \
    float4v sA[4][4]; \
    _Pragma("unroll") for (int qt = 0; qt < 4; ++qt) \
        _Pragma("unroll") for (int nt = 0; nt < 4; ++nt) \
            sA[qt][nt] = (float4v){0.f, 0.f, 0.f, 0.f}; \
    /* ---- QK^T: kit-outer, kb hoisted (8 LDS reads total) ---- */ \
    _Pragma("unroll") for (int kit = 0; kit < 2; ++kit) { \
        const int seg = ((kit * 4 + quad) ^ xs) * 8; \
        short8 kb[4]; \
        _Pragma("unroll") for (int nt = 0; nt < 4; ++nt) \
            kb[nt] = *(const short8*)&Ks[cur][(16 * nt + l) * 64 + seg]; \
        __builtin_amdgcn_s_setprio(1); \
        _Pragma("unroll") for (int qt = 0; qt < 4; ++qt) \
            _Pragma("unroll") for (int nt = 0; nt < 4; ++nt) \
                sA[qt][nt] = __builtin_amdgcn_mfma_f32_16x16x32_bf16(qa[qt][kit], kb[nt], sA[qt][nt], 0, 0, 0); \
        __builtin_amdgcn_s_setprio(0); \
    } \
    /* ---- V fragments hoisted (8 LDS reads total) ---- */ \
    short8 vb[2][4]; \
    _Pragma("unroll") for (int kit = 0; kit < 2; ++kit) { \
        const int seg = ((kit * 4 + quad) ^ xs) * 8; \
        _Pragma("unroll") for (int dt = 0; dt < 4; ++dt) \
            vb[kit][dt] = *(const short8*)&Vs[cur][(16 * dt + l) * 64 + seg]; \
    } \
    /* ---- per-qt: softmax -> Ps stripe -> PV (stripe reused) ---- */ \
    _Pragma("unroll") for (int qt = 0; qt < 4; ++qt) { \
        _Pragma("unroll") for (int nt = 0; nt < 4; ++nt) { \
            _Pragma("unroll") for (int i = 0; i < 4; ++i) { \
                const float p = EXP2(fminf(sA[qt][nt][i], 80.f)); \
                const unsigned pu = __float_as_uint(p); \
                l_part[qt][i] += __uint_as_float(pu & 0xFFFF0000u); \
                Ps[(wv * 16 + quad * 4 + i) * 72 + 16 * nt + l] = \
                    (unsigned short)(pu >> 16); \
            } \
        } \
        __builtin_amdgcn_s_setprio(1); \
        _Pragma("unroll") for (int kit = 0; kit < 2; ++kit) { \
            const short8 pa = *(const short8*)&Ps[(wv * 16 + l) * 72 + kit * 32 + quad * 8]; \
            _Pragma("unroll") for (int dt = 0; dt < 4; ++dt) \
                acc[qt][dt] = __builtin_amdgcn_mfma_f32_16x16x32_bf16(pa, vb[kit][dt], acc[qt][dt], 0, 0, 0); \
        } \
        __builtin_amdgcn_s_setprio(0); \
    } \
  } while (0)

__global__ __attribute__((amdgpu_flat_work_group_size(256, 256),
                          amdgpu_waves_per_eu(2)))
void attn_kernel(const unsigned short* __restrict__ qkv,
                 const unsigned short* __restrict__ VT,
                 unsigned short* __restrict__ yH,
                 unsigned short* __restrict__ yL)
{
    __shared__ __align__(16) unsigned short Qs[256 * 64];       // 32 KB
    __shared__ __align__(16) unsigned short Ks[2][64 * 64];     // 16 KB
    __shared__ __align__(16) unsigned short Vs[2][64 * 64];     // 16 KB
    __shared__ __align__(16) unsigned short Ps[64 * 72];        //  9 KB

    const int tid = threadIdx.x;
    // T1 XCD swizzle (512 blocks, 2/CU): XCD k handles bh in [8k, 8k+8),
    // each with all 8 q-tiles -> per-XCD K/V working set 4MB ~ L2.
    const int lid = blockIdx.x;
    const int work = (lid & 7) * 64 + (lid >> 3);
    const int q0 = (work & 7) * 256;
    const int bh = work >> 3;
    const int b = bh >> 4;
    const int hoff = (bh & 15) * 64;
    const long base = (long)(b * TT);
    const long vtbase = (long)bh * 64 * TT;

    const int lane = tid & 63;
    const int wv = tid >> 6;
    const int l = lane & 15;
    const int quad = lane >> 4;
    const int xs = l & 7;

    const int u0 = (wv << 7) + lane, u1 = u0 + 64;
    const int r0 = u0 >> 3, s0 = (u0 & 7) ^ (r0 & 7);
    const int r1 = u1 >> 3, s1 = (u1 & 7) ^ (r1 & 7);

    // ---- Q staging: 256 rows x 64, 8 slots/thread, same XOR layout ----
    #pragma unroll
    for (int i = 0; i < 8; ++i) {
        const int u = (wv << 9) + (i << 6) + lane;
        const int r = u >> 3, s = (u & 7) ^ (r & 7);
        async16(qkv + (base + q0 + r) * F3 + hoff + s * 8, &Qs[u * 8]);
    }
    STAGEKV(0, 0);
    VMW(0); BAR();

    // ---- Q fragments -> registers (Qs dead afterwards) ----
    short8 qa[4][2];
    #pragma unroll
    for (int qt = 0; qt < 4; ++qt)
        #pragma unroll
        for (int kit = 0; kit < 2; ++kit) {
            const int seg = ((kit * 4 + quad) ^ xs) * 8;
            qa[qt][kit] = *(const short8*)&Qs[(wv * 64 + qt * 16 + l) * 64 + seg];
        }

    float4v acc[4][4];
    float l_part[4][4];
    #pragma unroll
    for (int qt = 0; qt < 4; ++qt)
        #pragma unroll
        for (int dt = 0; dt < 4; ++dt) {
            acc[qt][dt] = (float4v){0.f, 0.f, 0.f, 0.f};
            l_part[qt][dt] = 0.f;
        }

    #pragma unroll 1
    for (int t = 0; t < TT / 64 - 1; ++t) {
        const int cur = t & 1;
        STAGEKV((t + 1) * 64, cur ^ 1);   // buf cur^1 released at prev BAR
        VMW(4);                           // tile t landed; t+1 in flight
        BAR();
        ATTN_TILE(cur);
        BAR();
    }
    VMW(0);
    BAR();
    ATTN_TILE(1);

    // ---- deferred 16-lane reductions, normalize, write y hi/lo ----
    #pragma unroll
    for (int qt = 0; qt < 4; ++qt)
        #pragma unroll
        for (int i = 0; i < 4; ++i) {
            const float inv_l = 1.f / red16_sum(l_part[qt][i]);
            const long row = base + q0 + wv * 64 + qt * 16 + quad * 4 + i;
            #pragma unroll
            for (int dt = 0; dt < 4; ++dt) {
                const float o = acc[qt][dt][i] * inv_l;
                const unsigned short hh = f2bf(o);
                yH[row * CC + hoff + 16 * dt + l] = hh;
                yL[row * CC + hoff + 16 * dt + l] = f2bf(o - bf2f(hh));
            }
        }
}

extern "C" void kernel_launch(void* const* d_in, const int* in_sizes, int n_in,
                              void* d_out, int out_size, void* d_ws, size_t ws_size,
                              hipStream_t stream) {
    const float* x      = (const float*)d_in[0];
    const float* w_attn = (const float*)d_in[1];
    const float* b_attn = (const float*)d_in[2];
    const float* w_proj = (const float*)d_in[3];
    const float* b_proj = (const float*)d_in[4];
    float* out = (float*)d_out;

    // ws layout (bytes):
    // qkv 50.3MB | VT 16.8 | xyH 16.8 | xyL 16.8 | WaH 6.3 | WaL 6.3 |
    // WpH 2.1 | WpL 2.1  => ~117.5 MB
    char* wsb = (char*)d_ws;
    unsigned short* qkv = (unsigned short*)(wsb);
    unsigned short* VT  = (unsigned short*)(wsb + 50331648);
    unsigned short* xyH = (unsigned short*)(wsb + 67108864);
    unsigned short* xyL = (unsigned short*)(wsb + 83886080);
    unsigned short* WaH = (unsigned short*)(wsb + 100663296);
    unsigned short* WaL = (unsigned short*)(wsb + 106954752);
    unsigned short* WpH = (unsigned short*)(wsb + 113246208);
    unsigned short* WpL = (unsigned short*)(wsb + 115343360);

    // 0) weight transpose+split, x split
    prep_w<<<dim3(F3 / 64, KDIM / 64), 256, 0, stream>>>(w_attn, WaH, WaL, F3);
    prep_w<<<dim3(CC / 64, KDIM / 64), 256, 0, stream>>>(w_proj, WpH, WpL, CC);
    split_f32<<<(NTOK * CC / 4) / 256, 256, 0, stream>>>(x, xyH, xyL);

    // 1) qkv = x @ w_attn + b_attn  (Q scaled by 0.125*log2e, V -> VT)
    gemm_split<<<dim3(F3 / 128, NTOK / 128), 256, 0, stream>>>(
        xyH, xyL, WaH, WaL, b_attn, qkv, VT, F3, 1);

    // 2) attention -> y (bf16 hi/lo; overwrites x-split which is dead)
    attn_kernel<<<dim3((TT / 256) * BB * HH), 256, 0, stream>>>(qkv, VT, xyH, xyL);

    // 3) out (fp32) = y @ w_proj + b_proj
    gemm_split<<<dim3(CC / 128, NTOK / 128), 256, 0, stream>>>(
        xyH, xyL, WpH, WpL, b_proj, out, (unsigned short*)nullptr, CC, 0);
}

// Round 6
// 407.766 us; speedup vs baseline: 1.1009x; 1.0053x over previous
//
#include <hip/hip_runtime.h>
#include <math.h>

// Problem constants
#define BB 4
#define TT 2048
#define CC 1024
#define HH 16
#define F3 3072          // 3*C
#define NTOK (BB*TT)     // 8192
#define KDIM 1024

typedef __attribute__((ext_vector_type(8))) short short8;            // 8 bf16
typedef __attribute__((ext_vector_type(8))) unsigned short ushort8;
typedef __attribute__((ext_vector_type(4))) unsigned short ushort4v;
typedef __attribute__((ext_vector_type(4))) float float4v;

static __device__ __forceinline__ unsigned short f2bf(float x) {
    union { float f; unsigned u; } v; v.f = x;
    unsigned r = v.u + 0x7fffu + ((v.u >> 16) & 1u);
    return (unsigned short)(r >> 16);
}
static __device__ __forceinline__ float bf2f(unsigned short h) {
    union { unsigned u; float f; } v; v.u = ((unsigned)h) << 16;
    return v.f;
}

// async 16B/lane global->LDS DMA; LDS dest = base + lane*16 (wave-uniform base)
static __device__ __forceinline__ void async16(const void* g, void* l) {
    __builtin_amdgcn_global_load_lds(
        (const __attribute__((address_space(1))) unsigned int*)g,
        (__attribute__((address_space(3))) unsigned int*)l, 16, 0, 0);
}

// DPP cross-lane (VALU pipe): ror8/ror4 + quad_perm xor2/xor1 = 16-lane butterfly
template <int C>
static __device__ __forceinline__ float dppf(float x) {
    return __int_as_float(
        __builtin_amdgcn_update_dpp(0, __float_as_int(x), C, 0xf, 0xf, true));
}
static __device__ __forceinline__ float red16_sum(float v) {
    v += dppf<0x128>(v);
    v += dppf<0x124>(v);
    v += dppf<0x4E>(v);
    v += dppf<0xB1>(v);
    return v;
}

#if __has_builtin(__builtin_amdgcn_exp2f)
#define EXP2(x) __builtin_amdgcn_exp2f(x)
#else
#define EXP2(x) __expf((x) * 0.6931471805599453f)
#endif

#define BAR()  asm volatile("s_barrier" ::: "memory")
#define VMW(n) asm volatile("s_waitcnt vmcnt(" #n ")" ::: "memory")

// ---------------------------------------------------------------------------
// prep_w: W[K,N] fp32 -> WtH/WtL [N][K] bf16 hi/lo (transpose + split).
// ---------------------------------------------------------------------------
__global__ __launch_bounds__(256) void prep_w(
    const float* __restrict__ W, unsigned short* __restrict__ WtH,
    unsigned short* __restrict__ WtL, int N)
{
    __shared__ float Ls[64][65];
    const int t = threadIdx.x;
    const int n0 = blockIdx.x * 64, k0 = blockIdx.y * 64;
    const int cc = t & 63, rr = t >> 6;
    #pragma unroll
    for (int i = 0; i < 16; ++i) {
        const int row = rr + 4 * i;
        Ls[row][cc] = W[(long)(k0 + row) * N + n0 + cc];
    }
    __syncthreads();
    const int n = t >> 2, seg = (t & 3) << 4;
    ushort8 h0, h1, l0, l1;
    #pragma unroll
    for (int j = 0; j < 8; ++j) {
        float x0 = Ls[seg + j][n];
        h0[j] = f2bf(x0); l0[j] = f2bf(x0 - bf2f(h0[j]));
        float x1 = Ls[seg + 8 + j][n];
        h1[j] = f2bf(x1); l1[j] = f2bf(x1 - bf2f(h1[j]));
    }
    const long o = (long)(n0 + n) * KDIM + k0 + seg;
    *(ushort8*)(WtH + o) = h0;     *(ushort8*)(WtH + o + 8) = h1;
    *(ushort8*)(WtL + o) = l0;     *(ushort8*)(WtL + o + 8) = l1;
}

// ---------------------------------------------------------------------------
// split_f32: X fp32 -> XH/XL bf16 hi/lo, elementwise.
// ---------------------------------------------------------------------------
__global__ __launch_bounds__(256) void split_f32(
    const float* __restrict__ X, unsigned short* __restrict__ XH,
    unsigned short* __restrict__ XL)
{
    const long i = (long)blockIdx.x * 256 + threadIdx.x;
    const float4 v = ((const float4*)X)[i];
    ushort4v h, lo;
    h[0] = f2bf(v.x); lo[0] = f2bf(v.x - bf2f(h[0]));
    h[1] = f2bf(v.y); lo[1] = f2bf(v.y - bf2f(h[1]));
    h[2] = f2bf(v.z); lo[2] = f2bf(v.z - bf2f(h[2]));
    h[3] = f2bf(v.w); lo[3] = f2bf(v.w - bf2f(h[3]));
    ((ushort4v*)XH)[i] = h;
    ((ushort4v*)XL)[i] = lo;
}

// ---------------------------------------------------------------------------
// gemm_split (R10 structure, unchanged): out[M,N] = (AH+AL)[M,K] @
// (BH+BL)^T[N,K] + bias, 3-term split-bf16 MFMA. 128x128 tile, BK=32,
// 4 waves, global_load_lds staging with XOR-swizzled unpadded LDS.
// ---------------------------------------------------------------------------
__global__ __launch_bounds__(256) void gemm_split(
    const unsigned short* __restrict__ AH, const unsigned short* __restrict__ AL,
    const unsigned short* __restrict__ BH, const unsigned short* __restrict__ BL,
    const float* __restrict__ bias, void* __restrict__ outp,
    unsigned short* __restrict__ VTp, int N, int mode)
{
    __shared__ __align__(16) unsigned short sAH[128 * 32];
    __shared__ __align__(16) unsigned short sAL[128 * 32];
    __shared__ __align__(16) unsigned short sBH[128 * 32];
    __shared__ __align__(16) unsigned short sBL[128 * 32];

    const int tid = threadIdx.x;
    const int n0 = blockIdx.x * 128, m0 = blockIdx.y * 128;
    const int lane = tid & 63, w = tid >> 6;
    const int wm = w >> 1, wn = w & 1;
    const int l = lane & 15, quad = lane >> 4;

    unsigned short* const sbuf = (w == 0) ? sAH : (w == 1) ? sAL
                               : (w == 2) ? sBH : sBL;
    const unsigned short* const gsrc =
        (w == 0) ? AH + (long)m0 * KDIM : (w == 1) ? AL + (long)m0 * KDIM
      : (w == 2) ? BH + (long)n0 * KDIM : BL + (long)n0 * KDIM;
    const int lrow = lane >> 2;
    const int lseg = ((lane & 3) - (lane >> 3)) & 3;
    const unsigned short* const gbase = gsrc + (long)lrow * KDIM + lseg * 8;
    unsigned short* const lbase = sbuf + lane * 8;

    const int swz = ((quad + (l >> 1)) & 3) * 8;

    float4v acc[4][4];
    #pragma unroll
    for (int mt = 0; mt < 4; ++mt)
        #pragma unroll
        for (int nt = 0; nt < 4; ++nt)
            acc[mt][nt] = (float4v){0.f, 0.f, 0.f, 0.f};

    for (int k0 = 0; k0 < KDIM; k0 += 32) {
        #pragma unroll
        for (int i = 0; i < 8; ++i)
            async16(gbase + (long)i * 16 * KDIM + k0, lbase + i * 512);
        __syncthreads();

        short8 fah[4], fal[4];
        #pragma unroll
        for (int mt = 0; mt < 4; ++mt) {
            const int off = (wm * 64 + mt * 16 + l) * 32 + swz;
            fah[mt] = *(const short8*)&sAH[off];
            fal[mt] = *(const short8*)&sAL[off];
        }
        #pragma unroll
        for (int nt = 0; nt < 4; ++nt) {
            const int off = (wn * 64 + nt * 16 + l) * 32 + swz;
            const short8 fbh = *(const short8*)&sBH[off];
            const short8 fbl = *(const short8*)&sBL[off];
            #pragma unroll
            for (int mt = 0; mt < 4; ++mt) {
                acc[mt][nt] = __builtin_amdgcn_mfma_f32_16x16x32_bf16(fah[mt], fbh, acc[mt][nt], 0, 0, 0);
                acc[mt][nt] = __builtin_amdgcn_mfma_f32_16x16x32_bf16(fah[mt], fbl, acc[mt][nt], 0, 0, 0);
                acc[mt][nt] = __builtin_amdgcn_mfma_f32_16x16x32_bf16(fal[mt], fbh, acc[mt][nt], 0, 0, 0);
            }
        }
        __syncthreads();
    }

    #pragma unroll
    for (int nt = 0; nt < 4; ++nt) {
        const int col = n0 + wn * 64 + nt * 16 + l;
        const float bv = bias[col];
        if (mode == 0) {
            #pragma unroll
            for (int mt = 0; mt < 4; ++mt)
                #pragma unroll
                for (int i = 0; i < 4; ++i) {
                    const long row = m0 + wm * 64 + mt * 16 + quad * 4 + i;
                    ((float*)outp)[row * N + col] = acc[mt][nt][i] + bv;
                }
        } else if (col < 2048) {
            const float sc = (col < 1024) ? 0.18033688011112042f : 1.0f;  // 0.125*log2(e)
            #pragma unroll
            for (int mt = 0; mt < 4; ++mt)
                #pragma unroll
                for (int i = 0; i < 4; ++i) {
                    const long row = m0 + wm * 64 + mt * 16 + quad * 4 + i;
                    ((unsigned short*)outp)[row * N + col] = f2bf((acc[mt][nt][i] + bv) * sc);
                }
        } else {
            const int d = col & 63;
            const int hh = (col >> 6) - 32;
            const int bb = m0 >> 11;
            const long vtoff = ((long)(bb * HH + hh) * 64 + d) * TT;
            #pragma unroll
            for (int mt = 0; mt < 4; ++mt) {
                const int t0 = (m0 & 2047) + wm * 64 + mt * 16 + quad * 4;
                ushort4v pk;
                #pragma unroll
                for (int i = 0; i < 4; ++i) pk[i] = f2bf(acc[mt][nt][i] + bv);
                *(ushort4v*)(VTp + vtoff + t0) = pk;
            }
        }
    }
}

// ---------------------------------------------------------------------------
// Flash attention, bf16 MFMA. R16 == R15 resubmitted (R15 bench was an
// infra double-failure with no profile; audit found no OOB, no divergent
// barrier, DMA dest = uniform-base + lane*16 everywhere, write-after-read
// fencing correct). Theory unchanged:
//  * attn is OCCUPANCY-bound (R14: no pipe > ~60us but wall = 170us at
//    2 waves/SIMD lockstep; R10->R12 3-vs-4 blocks/CU cost +31us).
//  * QBLK=256, 8 waves x 32 q-rows; acc[2][4]+sA[2][4]+qa[2][2] ~ 115 VGPR
//    -> 4 waves/SIMD (waves_per_eu(4)).
//  * LDS 68 KB: Q staged through the K/V double-buffer pre-loop
//    (VMW(0)+BAR -> qa regs -> __syncthreads -> stage tile0);
//    2 blocks/CU -> 16 waves/CU (2x R14).
//  * kb/vb shared by the qt-pair; per-tile 20 ds_read_b128 + 32 b16 writes.
//  * Math identities unchanged (XOR swizzle, exp2 fixed-max softmax,
//    truncation-consistent masked-l, per-wave Ps stripes, DPP reduce,
//    double-buffered K/V with counted vmcnt(2)).
// ---------------------------------------------------------------------------
#define STAGEKV(k0, bf) do { \
    async16(qkv + (base + (k0) + rK) * F3 + 1024 + hoff + sK * 8, &KV[bf][tid * 8]); \
    async16(VT + vtbase + (long)rK * TT + (k0) + sK * 8, &KV[2 + bf][tid * 8]); \
  } while (0)

#define ATTN_TILE(cur) do { \
    float4v sA[2][4]; \
    _Pragma("unroll") for (int qt = 0; qt < 2; ++qt) \
        _Pragma("unroll") for (int nt = 0; nt < 4; ++nt) \
            sA[qt][nt] = (float4v){0.f, 0.f, 0.f, 0.f}; \
    /* ---- QK^T: kb per (kit,nt), shared by the qt-pair ---- */ \
    __builtin_amdgcn_s_setprio(1); \
    _Pragma("unroll") for (int kit = 0; kit < 2; ++kit) { \
        const int seg = ((kit * 4 + quad) ^ xs) * 8; \
        _Pragma("unroll") for (int nt = 0; nt < 4; ++nt) { \
            const short8 kb = *(const short8*)&KV[cur][(16 * nt + l) * 64 + seg]; \
            sA[0][nt] = __builtin_amdgcn_mfma_f32_16x16x32_bf16(qa[0][kit], kb, sA[0][nt], 0, 0, 0); \
            sA[1][nt] = __builtin_amdgcn_mfma_f32_16x16x32_bf16(qa[1][kit], kb, sA[1][nt], 0, 0, 0); \
        } \
    } \
    __builtin_amdgcn_s_setprio(0); \
    /* ---- softmax both qt -> per-wave Ps stripes (32 rows) ---- */ \
    _Pragma("unroll") for (int qt = 0; qt < 2; ++qt) { \
        _Pragma("unroll") for (int nt = 0; nt < 4; ++nt) { \
            _Pragma("unroll") for (int i = 0; i < 4; ++i) { \
                const float p = EXP2(fminf(sA[qt][nt][i], 80.f)); \
                const unsigned pu = __float_as_uint(p); \
                l_part[qt][i] += __uint_as_float(pu & 0xFFFF0000u); \
                Ps[(wv * 32 + qt * 16 + quad * 4 + i) * 72 + 16 * nt + l] = \
                    (unsigned short)(pu >> 16); \
            } \
        } \
    } \
    /* ---- PV: pa per (kit,qt), vb per (kit,dt) shared by the pair ---- */ \
    __builtin_amdgcn_s_setprio(1); \
    _Pragma("unroll") for (int kit = 0; kit < 2; ++kit) { \
        const short8 pa0 = *(const short8*)&Ps[(wv * 32 + l) * 72 + kit * 32 + quad * 8]; \
        const short8 pa1 = *(const short8*)&Ps[(wv * 32 + 16 + l) * 72 + kit * 32 + quad * 8]; \
        const int seg = ((kit * 4 + quad) ^ xs) * 8; \
        _Pragma("unroll") for (int dt = 0; dt < 4; ++dt) { \
            const short8 vb = *(const short8*)&KV[2 + cur][(16 * dt + l) * 64 + seg]; \
            acc[0][dt] = __builtin_amdgcn_mfma_f32_16x16x32_bf16(pa0, vb, acc[0][dt], 0, 0, 0); \
            acc[1][dt] = __builtin_amdgcn_mfma_f32_16x16x32_bf16(pa1, vb, acc[1][dt], 0, 0, 0); \
        } \
    } \
    __builtin_amdgcn_s_setprio(0); \
  } while (0)

__global__ __attribute__((amdgpu_flat_work_group_size(512, 512),
                          amdgpu_waves_per_eu(4)))
void attn_kernel(const unsigned short* __restrict__ qkv,
                 const unsigned short* __restrict__ VT,
                 unsigned short* __restrict__ yH,
                 unsigned short* __restrict__ yL)
{
    // KV[0]=K buf0, KV[1]=K buf1, KV[2]=V buf0, KV[3]=V buf1 (32 KB);
    // Q (32 KB) is staged through this whole region pre-loop.
    __shared__ __align__(16) unsigned short KV[4][64 * 64];     // 32 KB
    __shared__ __align__(16) unsigned short Ps[256 * 72];       // 36 KB

    const int tid = threadIdx.x;
    // T1 XCD swizzle (512 blocks, 2/CU, all resident): XCD k <- bh in
    // [8k, 8k+8) x 8 q-tiles -> per-XCD K/V working set ~4MB ~ L2.
    const int lid = blockIdx.x;
    const int work = (lid & 7) * 64 + (lid >> 3);
    const int q0 = (work & 7) * 256;
    const int bh = work >> 3;
    const int b = bh >> 4;
    const int hoff = (bh & 15) * 64;
    const long base = (long)(b * TT);
    const long vtbase = (long)bh * 64 * TT;

    const int lane = tid & 63;
    const int wv = tid >> 6;
    const int l = lane & 15;
    const int quad = lane >> 4;
    const int xs = l & 7;

    // K/V staging: 1 slot/thread (512 slots = 64 rows x 64 cols, XOR layout)
    const int rK = tid >> 3;
    const int sK = (tid & 7) ^ (rK & 7);

    unsigned short* const KVf = &KV[0][0];

    // ---- Q staging through the KV region: 4 slots/thread ----
    #pragma unroll
    for (int i = 0; i < 4; ++i) {
        const int u = i * 512 + tid;
        const int r = u >> 3, s = (u & 7) ^ (r & 7);
        async16(qkv + (base + q0 + r) * F3 + hoff + s * 8, &KVf[u * 8]);
    }
    VMW(0); BAR();          // all Q writes visible to all waves

    // ---- Q fragments -> registers ----
    short8 qa[2][2];
    #pragma unroll
    for (int qt = 0; qt < 2; ++qt)
        #pragma unroll
        for (int kit = 0; kit < 2; ++kit) {
            const int seg = ((kit * 4 + quad) ^ xs) * 8;
            qa[qt][kit] = *(const short8*)&KVf[(wv * 32 + qt * 16 + l) * 64 + seg];
        }
    __syncthreads();        // qa reads complete before KV region is reused

    float4v acc[2][4];
    float l_part[2][4];
    #pragma unroll
    for (int qt = 0; qt < 2; ++qt)
        #pragma unroll
        for (int dt = 0; dt < 4; ++dt) {
            acc[qt][dt] = (float4v){0.f, 0.f, 0.f, 0.f};
            l_part[qt][dt] = 0.f;
        }

    // ---- tile 0 into buf 0 ----
    STAGEKV(0, 0);
    VMW(0); BAR();

    #pragma unroll 1
    for (int t = 0; t < TT / 64 - 1; ++t) {
        const int cur = t & 1;
        STAGEKV((t + 1) * 64, cur ^ 1);   // buf cur^1 released at prev BAR
        VMW(2);                           // tile t landed; t+1 in flight
        BAR();
        ATTN_TILE(cur);
        BAR();
    }
    VMW(0);
    BAR();
    ATTN_TILE(1);

    // ---- deferred 16-lane reductions, normalize, write y hi/lo ----
    #pragma unroll
    for (int qt = 0; qt < 2; ++qt)
        #pragma unroll
        for (int i = 0; i < 4; ++i) {
            const float inv_l = 1.f / red16_sum(l_part[qt][i]);
            const long row = base + q0 + wv * 32 + qt * 16 + quad * 4 + i;
            #pragma unroll
            for (int dt = 0; dt < 4; ++dt) {
                const float o = acc[qt][dt][i] * inv_l;
                const unsigned short hh = f2bf(o);
                yH[row * CC + hoff + 16 * dt + l] = hh;
                yL[row * CC + hoff + 16 * dt + l] = f2bf(o - bf2f(hh));
            }
        }
}

extern "C" void kernel_launch(void* const* d_in, const int* in_sizes, int n_in,
                              void* d_out, int out_size, void* d_ws, size_t ws_size,
                              hipStream_t stream) {
    const float* x      = (const float*)d_in[0];
    const float* w_attn = (const float*)d_in[1];
    const float* b_attn = (const float*)d_in[2];
    const float* w_proj = (const float*)d_in[3];
    const float* b_proj = (const float*)d_in[4];
    float* out = (float*)d_out;

    // ws layout (bytes):
    // qkv 50.3MB | VT 16.8 | xyH 16.8 | xyL 16.8 | WaH 6.3 | WaL 6.3 |
    // WpH 2.1 | WpL 2.1  => ~117.5 MB
    char* wsb = (char*)d_ws;
    unsigned short* qkv = (unsigned short*)(wsb);
    unsigned short* VT  = (unsigned short*)(wsb + 50331648);
    unsigned short* xyH = (unsigned short*)(wsb + 67108864);
    unsigned short* xyL = (unsigned short*)(wsb + 83886080);
    unsigned short* WaH = (unsigned short*)(wsb + 100663296);
    unsigned short* WaL = (unsigned short*)(wsb + 106954752);
    unsigned short* WpH = (unsigned short*)(wsb + 113246208);
    unsigned short* WpL = (unsigned short*)(wsb + 115343360);

    // 0) weight transpose+split, x split
    prep_w<<<dim3(F3 / 64, KDIM / 64), 256, 0, stream>>>(w_attn, WaH, WaL, F3);
    prep_w<<<dim3(CC / 64, KDIM / 64), 256, 0, stream>>>(w_proj, WpH, WpL, CC);
    split_f32<<<(NTOK * CC / 4) / 256, 256, 0, stream>>>(x, xyH, xyL);

    // 1) qkv = x @ w_attn + b_attn  (Q scaled by 0.125*log2e, V -> VT)
    gemm_split<<<dim3(F3 / 128, NTOK / 128), 256, 0, stream>>>(
        xyH, xyL, WaH, WaL, b_attn, qkv, VT, F3, 1);

    // 2) attention -> y (bf16 hi/lo; overwrites x-split which is dead)
    attn_kernel<<<dim3((TT / 256) * BB * HH), 512, 0, stream>>>(qkv, VT, xyH, xyL);

    // 3) out (fp32) = y @ w_proj + b_proj
    gemm_split<<<dim3(CC / 128, NTOK / 128), 256, 0, stream>>>(
        xyH, xyL, WpH, WpL, b_proj, out, (unsigned short*)nullptr, CC, 0);
}

// Round 7
// 315.954 us; speedup vs baseline: 1.4208x; 1.2906x over previous
//
#include <hip/hip_runtime.h>
#include <math.h>

// Problem constants
#define BB 4
#define TT 2048
#define CC 1024
#define HH 16
#define F3 3072          // 3*C
#define NTOK (BB*TT)     // 8192
#define KDIM 1024

typedef __attribute__((ext_vector_type(8))) short short8;            // 8 bf16
typedef __attribute__((ext_vector_type(8))) unsigned short ushort8;
typedef __attribute__((ext_vector_type(8))) _Float16 half8;          // 8 fp16
typedef __attribute__((ext_vector_type(4))) unsigned short ushort4v;
typedef __attribute__((ext_vector_type(4))) float float4v;

static __device__ __forceinline__ unsigned short f2bf(float x) {
    union { float f; unsigned u; } v; v.f = x;
    unsigned r = v.u + 0x7fffu + ((v.u >> 16) & 1u);
    return (unsigned short)(r >> 16);
}
static __device__ __forceinline__ float bf2f(unsigned short h) {
    union { unsigned u; float f; } v; v.u = ((unsigned)h) << 16;
    return v.f;
}
static __device__ __forceinline__ unsigned short f2h(float x) {
    union { _Float16 h; unsigned short u; } v; v.h = (_Float16)x; return v.u;
}

// async 16B/lane global->LDS DMA; LDS dest = base + lane*16 (wave-uniform base)
static __device__ __forceinline__ void async16(const void* g, void* l) {
    __builtin_amdgcn_global_load_lds(
        (const __attribute__((address_space(1))) unsigned int*)g,
        (__attribute__((address_space(3))) unsigned int*)l, 16, 0, 0);
}

// DPP cross-lane (VALU pipe): ror8/ror4 + quad_perm xor2/xor1 = 16-lane butterfly
template <int C>
static __device__ __forceinline__ float dppf(float x) {
    return __int_as_float(
        __builtin_amdgcn_update_dpp(0, __float_as_int(x), C, 0xf, 0xf, true));
}
static __device__ __forceinline__ float red16_sum(float v) {
    v += dppf<0x128>(v);
    v += dppf<0x124>(v);
    v += dppf<0x4E>(v);
    v += dppf<0xB1>(v);
    return v;
}

#if __has_builtin(__builtin_amdgcn_exp2f)
#define EXP2(x) __builtin_amdgcn_exp2f(x)
#else
#define EXP2(x) __expf((x) * 0.6931471805599453f)
#endif

#define BAR()  asm volatile("s_barrier" ::: "memory")
#define VMW(n) asm volatile("s_waitcnt vmcnt(" #n ")" ::: "memory")

// ---------------------------------------------------------------------------
// prep_w: W[K,N] fp32 -> WtH/WtL [N][K] bf16 hi/lo (transpose + split).
// Still used for w_proj (final output needs the exact 3-term path).
// ---------------------------------------------------------------------------
__global__ __launch_bounds__(256) void prep_w(
    const float* __restrict__ W, unsigned short* __restrict__ WtH,
    unsigned short* __restrict__ WtL, int N)
{
    __shared__ float Ls[64][65];
    const int t = threadIdx.x;
    const int n0 = blockIdx.x * 64, k0 = blockIdx.y * 64;
    const int cc = t & 63, rr = t >> 6;
    #pragma unroll
    for (int i = 0; i < 16; ++i) {
        const int row = rr + 4 * i;
        Ls[row][cc] = W[(long)(k0 + row) * N + n0 + cc];
    }
    __syncthreads();
    const int n = t >> 2, seg = (t & 3) << 4;
    ushort8 h0, h1, l0, l1;
    #pragma unroll
    for (int j = 0; j < 8; ++j) {
        float x0 = Ls[seg + j][n];
        h0[j] = f2bf(x0); l0[j] = f2bf(x0 - bf2f(h0[j]));
        float x1 = Ls[seg + 8 + j][n];
        h1[j] = f2bf(x1); l1[j] = f2bf(x1 - bf2f(h1[j]));
    }
    const long o = (long)(n0 + n) * KDIM + k0 + seg;
    *(ushort8*)(WtH + o) = h0;     *(ushort8*)(WtH + o + 8) = h1;
    *(ushort8*)(WtL + o) = l0;     *(ushort8*)(WtL + o + 8) = l1;
}

// ---------------------------------------------------------------------------
// prep_w16: W[K,N] fp32 -> WtF [N][K] fp16 single (transpose + convert).
// R17: the qkv GEMM output is rounded to 16-bit anyway; fp16 single-term
// GEMM error (~3e-4 abs) < bf16 storage rounding the pipeline already has.
// ---------------------------------------------------------------------------
__global__ __launch_bounds__(256) void prep_w16(
    const float* __restrict__ W, unsigned short* __restrict__ WtF, int N)
{
    __shared__ float Ls[64][65];
    const int t = threadIdx.x;
    const int n0 = blockIdx.x * 64, k0 = blockIdx.y * 64;
    const int cc = t & 63, rr = t >> 6;
    #pragma unroll
    for (int i = 0; i < 16; ++i) {
        const int row = rr + 4 * i;
        Ls[row][cc] = W[(long)(k0 + row) * N + n0 + cc];
    }
    __syncthreads();
    const int n = t >> 2, seg = (t & 3) << 4;
    ushort8 h0, h1;
    #pragma unroll
    for (int j = 0; j < 8; ++j) {
        h0[j] = f2h(Ls[seg + j][n]);
        h1[j] = f2h(Ls[seg + 8 + j][n]);
    }
    const long o = (long)(n0 + n) * KDIM + k0 + seg;
    *(ushort8*)(WtF + o) = h0;     *(ushort8*)(WtF + o + 8) = h1;
}

// ---------------------------------------------------------------------------
// split16: X fp32 -> XF fp16 single, elementwise.
// ---------------------------------------------------------------------------
__global__ __launch_bounds__(256) void split16(
    const float* __restrict__ X, unsigned short* __restrict__ XF)
{
    const long i = (long)blockIdx.x * 256 + threadIdx.x;
    const float4 v = ((const float4*)X)[i];
    ushort4v h;
    h[0] = f2h(v.x); h[1] = f2h(v.y); h[2] = f2h(v.z); h[3] = f2h(v.w);
    ((ushort4v*)XF)[i] = h;
}

// ---------------------------------------------------------------------------
// gemm16_qkv (R17, new): qkv[M,F3] = A[M,K]fp16 @ B[F3,K]^T fp16 + bias.
// Single fp16 MFMA term (3x less MFMA, 2x less staging than the 3-term
// split). m97 2-barrier structure: 128x128 tile, BK=64, 4 waves,
// global_load_lds, XOR swizzle stored_seg = (seg + row) & 7 (8 lanes per
// 16B bank-group per ds_read_b128 -> conflict-free). Epilogue: Q cols
// (exp2-scale folded) and K cols -> fp16; V cols -> bf16 into VT.
// ---------------------------------------------------------------------------
__global__ __launch_bounds__(256) void gemm16_qkv(
    const unsigned short* __restrict__ A, const unsigned short* __restrict__ B,
    const float* __restrict__ bias, unsigned short* __restrict__ qkvp,
    unsigned short* __restrict__ VTp)
{
    __shared__ __align__(16) unsigned short sA[128 * 64];   // 16 KB
    __shared__ __align__(16) unsigned short sB[128 * 64];   // 16 KB

    const int tid = threadIdx.x;
    const int n0 = blockIdx.x * 128, m0 = blockIdx.y * 128;
    const int lane = tid & 63, w = tid >> 6;
    const int wm = w >> 1, wn = w & 1;
    const int l = lane & 15, quad = lane >> 4;

    // staging: waves 0-1 -> sA, waves 2-3 -> sB; 8 slots/thread.
    unsigned short* const sbuf = (w < 2) ? sA : sB;
    const unsigned short* const gsrc = (w < 2) ? A + (long)m0 * KDIM
                                               : B + (long)n0 * KDIM;
    const int p128 = (w & 1) * 64 + lane;   // 0..127 within the array's pair

    float4v acc[4][4];
    #pragma unroll
    for (int mt = 0; mt < 4; ++mt)
        #pragma unroll
        for (int nt = 0; nt < 4; ++nt)
            acc[mt][nt] = (float4v){0.f, 0.f, 0.f, 0.f};

    for (int k0 = 0; k0 < KDIM; k0 += 64) {
        #pragma unroll
        for (int i = 0; i < 8; ++i) {
            const int u = i * 128 + p128;          // slot 0..1023
            const int r = u >> 3, ps = u & 7;      // LDS row, stored seg
            const int s = (ps - r) & 7;            // logical seg (inverse swz)
            async16(gsrc + (long)r * KDIM + k0 + s * 8, sbuf + u * 8);
        }
        __syncthreads();

        #pragma unroll
        for (int ks = 0; ks < 2; ++ks) {
            half8 fa[4];
            #pragma unroll
            for (int mt = 0; mt < 4; ++mt) {
                const int row = wm * 64 + mt * 16 + l;
                fa[mt] = *(const half8*)&sA[row * 64 + ((ks * 4 + quad + row) & 7) * 8];
            }
            #pragma unroll
            for (int nt = 0; nt < 4; ++nt) {
                const int row = wn * 64 + nt * 16 + l;
                const half8 fb = *(const half8*)&sB[row * 64 + ((ks * 4 + quad + row) & 7) * 8];
                #pragma unroll
                for (int mt = 0; mt < 4; ++mt)
                    acc[mt][nt] = __builtin_amdgcn_mfma_f32_16x16x32_f16(fa[mt], fb, acc[mt][nt], 0, 0, 0);
            }
        }
        __syncthreads();
    }

    #pragma unroll
    for (int nt = 0; nt < 4; ++nt) {
        const int col = n0 + wn * 64 + nt * 16 + l;
        const float bv = bias[col];
        if (col < 2048) {
            const float sc = (col < 1024) ? 0.18033688011112042f : 1.0f;  // 0.125*log2(e)
            #pragma unroll
            for (int mt = 0; mt < 4; ++mt)
                #pragma unroll
                for (int i = 0; i < 4; ++i) {
                    const long row = m0 + wm * 64 + mt * 16 + quad * 4 + i;
                    qkvp[row * F3 + col] = f2h((acc[mt][nt][i] + bv) * sc);
                }
        } else {
            const int d = col & 63;
            const int hh = (col >> 6) - 32;
            const int bb = m0 >> 11;
            const long vtoff = ((long)(bb * HH + hh) * 64 + d) * TT;
            #pragma unroll
            for (int mt = 0; mt < 4; ++mt) {
                const int t0 = (m0 & 2047) + wm * 64 + mt * 16 + quad * 4;
                ushort4v pk;
                #pragma unroll
                for (int i = 0; i < 4; ++i) pk[i] = f2bf(acc[mt][nt][i] + bv);
                *(ushort4v*)(VTp + vtoff + t0) = pk;
            }
        }
    }
}

// ---------------------------------------------------------------------------
// gemm_split (unchanged R10 structure): used for the FINAL proj GEMM only
// (fp32 output needs the exact 3-term split-bf16 path).
// ---------------------------------------------------------------------------
__global__ __launch_bounds__(256) void gemm_split(
    const unsigned short* __restrict__ AH, const unsigned short* __restrict__ AL,
    const unsigned short* __restrict__ BH, const unsigned short* __restrict__ BL,
    const float* __restrict__ bias, void* __restrict__ outp,
    unsigned short* __restrict__ VTp, int N, int mode)
{
    __shared__ __align__(16) unsigned short sAH[128 * 32];
    __shared__ __align__(16) unsigned short sAL[128 * 32];
    __shared__ __align__(16) unsigned short sBH[128 * 32];
    __shared__ __align__(16) unsigned short sBL[128 * 32];

    const int tid = threadIdx.x;
    const int n0 = blockIdx.x * 128, m0 = blockIdx.y * 128;
    const int lane = tid & 63, w = tid >> 6;
    const int wm = w >> 1, wn = w & 1;
    const int l = lane & 15, quad = lane >> 4;

    unsigned short* const sbuf = (w == 0) ? sAH : (w == 1) ? sAL
                               : (w == 2) ? sBH : sBL;
    const unsigned short* const gsrc =
        (w == 0) ? AH + (long)m0 * KDIM : (w == 1) ? AL + (long)m0 * KDIM
      : (w == 2) ? BH + (long)n0 * KDIM : BL + (long)n0 * KDIM;
    const int lrow = lane >> 2;
    const int lseg = ((lane & 3) - (lane >> 3)) & 3;
    const unsigned short* const gbase = gsrc + (long)lrow * KDIM + lseg * 8;
    unsigned short* const lbase = sbuf + lane * 8;

    const int swz = ((quad + (l >> 1)) & 3) * 8;

    float4v acc[4][4];
    #pragma unroll
    for (int mt = 0; mt < 4; ++mt)
        #pragma unroll
        for (int nt = 0; nt < 4; ++nt)
            acc[mt][nt] = (float4v){0.f, 0.f, 0.f, 0.f};

    for (int k0 = 0; k0 < KDIM; k0 += 32) {
        #pragma unroll
        for (int i = 0; i < 8; ++i)
            async16(gbase + (long)i * 16 * KDIM + k0, lbase + i * 512);
        __syncthreads();

        short8 fah[4], fal[4];
        #pragma unroll
        for (int mt = 0; mt < 4; ++mt) {
            const int off = (wm * 64 + mt * 16 + l) * 32 + swz;
            fah[mt] = *(const short8*)&sAH[off];
            fal[mt] = *(const short8*)&sAL[off];
        }
        #pragma unroll
        for (int nt = 0; nt < 4; ++nt) {
            const int off = (wn * 64 + nt * 16 + l) * 32 + swz;
            const short8 fbh = *(const short8*)&sBH[off];
            const short8 fbl = *(const short8*)&sBL[off];
            #pragma unroll
            for (int mt = 0; mt < 4; ++mt) {
                acc[mt][nt] = __builtin_amdgcn_mfma_f32_16x16x32_bf16(fah[mt], fbh, acc[mt][nt], 0, 0, 0);
                acc[mt][nt] = __builtin_amdgcn_mfma_f32_16x16x32_bf16(fah[mt], fbl, acc[mt][nt], 0, 0, 0);
                acc[mt][nt] = __builtin_amdgcn_mfma_f32_16x16x32_bf16(fal[mt], fbh, acc[mt][nt], 0, 0, 0);
            }
        }
        __syncthreads();
    }

    #pragma unroll
    for (int nt = 0; nt < 4; ++nt) {
        const int col = n0 + wn * 64 + nt * 16 + l;
        const float bv = bias[col];
        #pragma unroll
        for (int mt = 0; mt < 4; ++mt)
            #pragma unroll
            for (int i = 0; i < 4; ++i) {
                const long row = m0 + wm * 64 + mt * 16 + quad * 4 + i;
                ((float*)outp)[row * N + col] = acc[mt][nt][i] + bv;
            }
    }
    (void)VTp; (void)mode;
}

// ---------------------------------------------------------------------------
// Flash attention. R17 = R16 structure (passed, current best) with Q/K in
// fp16: QK^T uses mfma_f32_16x16x32_f16 (C/D layout dtype-independent).
// V/P stay bf16 (P spans up to 2^80 -> needs bf16 range; MFMA operands
// must match). All other identities unchanged from R16.
// ---------------------------------------------------------------------------
#define STAGEKV(k0, bf) do { \
    async16(qkv + (base + (k0) + rK) * F3 + 1024 + hoff + sK * 8, &KV[bf][tid * 8]); \
    async16(VT + vtbase + (long)rK * TT + (k0) + sK * 8, &KV[2 + bf][tid * 8]); \
  } while (0)

#define ATTN_TILE(cur) do { \
    float4v sA[2][4]; \
    _Pragma("unroll") for (int qt = 0; qt < 2; ++qt) \
        _Pragma("unroll") for (int nt = 0; nt < 4; ++nt) \
            sA[qt][nt] = (float4v){0.f, 0.f, 0.f, 0.f}; \
    /* ---- QK^T (fp16): kb per (kit,nt), shared by the qt-pair ---- */ \
    __builtin_amdgcn_s_setprio(1); \
    _Pragma("unroll") for (int kit = 0; kit < 2; ++kit) { \
        const int seg = ((kit * 4 + quad) ^ xs) * 8; \
        _Pragma("unroll") for (int nt = 0; nt < 4; ++nt) { \
            const half8 kb = *(const half8*)&KV[cur][(16 * nt + l) * 64 + seg]; \
            sA[0][nt] = __builtin_amdgcn_mfma_f32_16x16x32_f16(qa[0][kit], kb, sA[0][nt], 0, 0, 0); \
            sA[1][nt] = __builtin_amdgcn_mfma_f32_16x16x32_f16(qa[1][kit], kb, sA[1][nt], 0, 0, 0); \
        } \
    } \
    __builtin_amdgcn_s_setprio(0); \
    /* ---- softmax both qt -> per-wave Ps stripes (32 rows) ---- */ \
    _Pragma("unroll") for (int qt = 0; qt < 2; ++qt) { \
        _Pragma("unroll") for (int nt = 0; nt < 4; ++nt) { \
            _Pragma("unroll") for (int i = 0; i < 4; ++i) { \
                const float p = EXP2(fminf(sA[qt][nt][i], 80.f)); \
                const unsigned pu = __float_as_uint(p); \
                l_part[qt][i] += __uint_as_float(pu & 0xFFFF0000u); \
                Ps[(wv * 32 + qt * 16 + quad * 4 + i) * 72 + 16 * nt + l] = \
                    (unsigned short)(pu >> 16); \
            } \
        } \
    } \
    /* ---- PV (bf16): pa per (kit,qt), vb shared by the pair ---- */ \
    __builtin_amdgcn_s_setprio(1); \
    _Pragma("unroll") for (int kit = 0; kit < 2; ++kit) { \
        const short8 pa0 = *(const short8*)&Ps[(wv * 32 + l) * 72 + kit * 32 + quad * 8]; \
        const short8 pa1 = *(const short8*)&Ps[(wv * 32 + 16 + l) * 72 + kit * 32 + quad * 8]; \
        const int seg = ((kit * 4 + quad) ^ xs) * 8; \
        _Pragma("unroll") for (int dt = 0; dt < 4; ++dt) { \
            const short8 vb = *(const short8*)&KV[2 + cur][(16 * dt + l) * 64 + seg]; \
            acc[0][dt] = __builtin_amdgcn_mfma_f32_16x16x32_bf16(pa0, vb, acc[0][dt], 0, 0, 0); \
            acc[1][dt] = __builtin_amdgcn_mfma_f32_16x16x32_bf16(pa1, vb, acc[1][dt], 0, 0, 0); \
        } \
    } \
    __builtin_amdgcn_s_setprio(0); \
  } while (0)

__global__ __attribute__((amdgpu_flat_work_group_size(512, 512),
                          amdgpu_waves_per_eu(4)))
void attn_kernel(const unsigned short* __restrict__ qkv,
                 const unsigned short* __restrict__ VT,
                 unsigned short* __restrict__ yH,
                 unsigned short* __restrict__ yL)
{
    // KV[0]=K buf0, KV[1]=K buf1, KV[2]=V buf0, KV[3]=V buf1 (32 KB);
    // Q (32 KB) is staged through this whole region pre-loop.
    __shared__ __align__(16) unsigned short KV[4][64 * 64];     // 32 KB
    __shared__ __align__(16) unsigned short Ps[256 * 72];       // 36 KB

    const int tid = threadIdx.x;
    // T1 XCD swizzle (512 blocks, 2/CU, all resident): XCD k <- bh in
    // [8k, 8k+8) x 8 q-tiles -> per-XCD K/V working set ~4MB ~ L2.
    const int lid = blockIdx.x;
    const int work = (lid & 7) * 64 + (lid >> 3);
    const int q0 = (work & 7) * 256;
    const int bh = work >> 3;
    const int b = bh >> 4;
    const int hoff = (bh & 15) * 64;
    const long base = (long)(b * TT);
    const long vtbase = (long)bh * 64 * TT;

    const int lane = tid & 63;
    const int wv = tid >> 6;
    const int l = lane & 15;
    const int quad = lane >> 4;
    const int xs = l & 7;

    // K/V staging: 1 slot/thread (512 slots = 64 rows x 64 cols, XOR layout)
    const int rK = tid >> 3;
    const int sK = (tid & 7) ^ (rK & 7);

    unsigned short* const KVf = &KV[0][0];

    // ---- Q staging through the KV region: 4 slots/thread ----
    #pragma unroll
    for (int i = 0; i < 4; ++i) {
        const int u = i * 512 + tid;
        const int r = u >> 3, s = (u & 7) ^ (r & 7);
        async16(qkv + (base + q0 + r) * F3 + hoff + s * 8, &KVf[u * 8]);
    }
    VMW(0); BAR();          // all Q writes visible to all waves

    // ---- Q fragments -> registers (fp16) ----
    half8 qa[2][2];
    #pragma unroll
    for (int qt = 0; qt < 2; ++qt)
        #pragma unroll
        for (int kit = 0; kit < 2; ++kit) {
            const int seg = ((kit * 4 + quad) ^ xs) * 8;
            qa[qt][kit] = *(const half8*)&KVf[(wv * 32 + qt * 16 + l) * 64 + seg];
        }
    __syncthreads();        // qa reads complete before KV region is reused

    float4v acc[2][4];
    float l_part[2][4];
    #pragma unroll
    for (int qt = 0; qt < 2; ++qt)
        #pragma unroll
        for (int dt = 0; dt < 4; ++dt) {
            acc[qt][dt] = (float4v){0.f, 0.f, 0.f, 0.f};
            l_part[qt][dt] = 0.f;
        }

    // ---- tile 0 into buf 0 ----
    STAGEKV(0, 0);
    VMW(0); BAR();

    #pragma unroll 1
    for (int t = 0; t < TT / 64 - 1; ++t) {
        const int cur = t & 1;
        STAGEKV((t + 1) * 64, cur ^ 1);   // buf cur^1 released at prev BAR
        VMW(2);                           // tile t landed; t+1 in flight
        BAR();
        ATTN_TILE(cur);
        BAR();
    }
    VMW(0);
    BAR();
    ATTN_TILE(1);

    // ---- deferred 16-lane reductions, normalize, write y hi/lo ----
    #pragma unroll
    for (int qt = 0; qt < 2; ++qt)
        #pragma unroll
        for (int i = 0; i < 4; ++i) {
            const float inv_l = 1.f / red16_sum(l_part[qt][i]);
            const long row = base + q0 + wv * 32 + qt * 16 + quad * 4 + i;
            #pragma unroll
            for (int dt = 0; dt < 4; ++dt) {
                const float o = acc[qt][dt][i] * inv_l;
                const unsigned short hh = f2bf(o);
                yH[row * CC + hoff + 16 * dt + l] = hh;
                yL[row * CC + hoff + 16 * dt + l] = f2bf(o - bf2f(hh));
            }
        }
}

extern "C" void kernel_launch(void* const* d_in, const int* in_sizes, int n_in,
                              void* d_out, int out_size, void* d_ws, size_t ws_size,
                              hipStream_t stream) {
    const float* x      = (const float*)d_in[0];
    const float* w_attn = (const float*)d_in[1];
    const float* b_attn = (const float*)d_in[2];
    const float* w_proj = (const float*)d_in[3];
    const float* b_proj = (const float*)d_in[4];
    float* out = (float*)d_out;

    // ws layout (bytes):
    // qkv 50.3MB | VT 16.8 | xF/yH 16.8 | yL 16.8 | WaF 6.3 |
    // WpH 2.1 | WpL 2.1  => ~111.2 MB  (xF dead after gemm16 -> reused as yH)
    char* wsb = (char*)d_ws;
    unsigned short* qkv = (unsigned short*)(wsb);
    unsigned short* VT  = (unsigned short*)(wsb + 50331648);
    unsigned short* xF  = (unsigned short*)(wsb + 67108864);   // later yH
    unsigned short* yL  = (unsigned short*)(wsb + 83886080);
    unsigned short* WaF = (unsigned short*)(wsb + 100663296);
    unsigned short* WpH = (unsigned short*)(wsb + 106954752);
    unsigned short* WpL = (unsigned short*)(wsb + 109051904);

    // 0) weight prep (w_attn -> fp16 single; w_proj -> bf16 hi/lo), x -> fp16
    prep_w16<<<dim3(F3 / 64, KDIM / 64), 256, 0, stream>>>(w_attn, WaF, F3);
    prep_w<<<dim3(CC / 64, KDIM / 64), 256, 0, stream>>>(w_proj, WpH, WpL, CC);
    split16<<<(NTOK * CC / 4) / 256, 256, 0, stream>>>(x, xF);

    // 1) qkv = x @ w_attn + b_attn, single fp16 MFMA term
    //    (Q scaled by 0.125*log2e -> fp16, K -> fp16, V -> bf16 VT)
    gemm16_qkv<<<dim3(F3 / 128, NTOK / 128), 256, 0, stream>>>(
        xF, WaF, b_attn, qkv, VT);

    // 2) attention -> y (bf16 hi/lo; yH overwrites xF which is dead)
    attn_kernel<<<dim3((TT / 256) * BB * HH), 512, 0, stream>>>(qkv, VT, xF, yL);

    // 3) out (fp32) = y @ w_proj + b_proj, exact 3-term split path
    gemm_split<<<dim3(CC / 128, NTOK / 128), 256, 0, stream>>>(
        xF, yL, WpH, WpL, b_proj, out, (unsigned short*)nullptr, CC, 0);
}